// Round 9
// baseline (680.675 us; speedup 1.0000x reference)
//
#include <hip/hip_runtime.h>
#include <hip/hip_bf16.h>

typedef unsigned short u16;
typedef unsigned int u32;
typedef __attribute__((ext_vector_type(8))) short short8;    // 8 bf16 MFMA A/B frag
typedef __attribute__((ext_vector_type(4))) float f32x4;

#define KS1 1.44269504f   // log2(e)
#define KS2 2.88539008f   // 2*log2(e)

__device__ __forceinline__ float bf2f(u16 u) {
    union { u32 i; float f; } v; v.i = ((u32)u) << 16; return v.f;
}
__device__ __forceinline__ u16 f2bf(float f) {            // RNE
    union { float f; u32 i; } v; v.f = f;
    u32 r = v.i + 0x7fffu + ((v.i >> 16) & 1u);
    return (u16)(r >> 16);
}
// pack two f32 -> two bf16 (truncation) in ONE v_perm (h state only)
__device__ __forceinline__ u32 pack_bf2(float lo, float hi) {
    return __builtin_amdgcn_perm(__float_as_uint(hi), __float_as_uint(lo), 0x07060302u);
}
// relu + RNE pack (epilogue intermediates)
__device__ __forceinline__ u32 pack_relu(float a, float b) {
    return (u32)f2bf(fmaxf(a, 0.f)) | ((u32)f2bf(fmaxf(b, 0.f)) << 16);
}
__device__ __forceinline__ f32x4 bias4(const u16* b) {
    uint2 u = *(const uint2*)b;
    f32x4 r;
    r[0] = bf2f((u16)(u.x & 0xffffu)); r[1] = bf2f((u16)(u.x >> 16));
    r[2] = bf2f((u16)(u.y & 0xffffu)); r[3] = bf2f((u16)(u.y >> 16));
    return r;
}
// LDS-only barrier: lgkmcnt(0)+s_barrier. Does NOT drain vmcnt, so the
// global_load_lds refills stay in flight across step barriers.
__device__ __forceinline__ void barrier_lds() {
    asm volatile("s_waitcnt lgkmcnt(0)" ::: "memory");
    __builtin_amdgcn_s_barrier();
}
// direct global->LDS 16B copy: lane writes at ldsbase + lane*16 (HW rule),
// so the XOR-swizzle is applied on the per-lane GLOBAL source instead.
__device__ __forceinline__ void gload_lds16(const u16* g, u16* l) {
    __builtin_amdgcn_global_load_lds(
        (const __attribute__((address_space(1))) u32*)(const void*)g,
        (__attribute__((address_space(3))) u32*)(void*)l, 16, 0, 0);
}
// XOR-swizzled exchange buffer (proven bank-free: <=2-way per 16-lane quarter).
__device__ __forceinline__ void xwrite(u16* buf, int D2, int row, int quad, int jt, u32 w0, u32 w1) {
    int ch = jt * 2 + (quad >> 1);
    *(uint2*)(buf + row * D2 + ((ch ^ (row & 7)) << 3) + ((quad & 1) << 2)) = (uint2){w0, w1};
}
__device__ __forceinline__ short8 xread(const u16* buf, int D2, int row, int quad, int kc) {
    return *(const short8*)(buf + row * D2 + (((kc * 4 + quad) ^ (row & 7)) << 3));
}
#define MFMA16 __builtin_amdgcn_mfma_f32_16x16x32_bf16

// ---------------------------------------------------------------------------
// k_pre: [0,gb) xp1 GEMM; [gb,gb+eb) edge cast; [gb+eb,+64) scaled weight copy
// ---------------------------------------------------------------------------
__global__ __launch_bounds__(256) void k_pre(
    const u16* __restrict__ X, const u16* __restrict__ pw, const u16* __restrict__ pb,
    u16* __restrict__ XP, int M, int gb,
    const int* __restrict__ e, float* __restrict__ eout, int n4, int eb,
    const u16* __restrict__ w1i, const u16* __restrict__ w1h,
    const u16* __restrict__ w2i, const u16* __restrict__ w2h,
    u16* __restrict__ wss)
{
    const int bid = blockIdx.x;
    const int tid = threadIdx.x;
    if (bid >= gb + eb) {
        int wb = bid - gb - eb;            // 0..63
        int mi = wb >> 4;
        const u16* Wsrc = (mi == 0) ? w1i : (mi == 1) ? w1h : (mi == 2) ? w2i : w2h;
        u16* Wdst = wss + (size_t)mi * 16384;
        int e0 = (wb & 15) * 1024 + tid * 4;
        int row = e0 >> 6;
        float sc = (row >= 128 && row < 192) ? KS2 : KS1;
        uint2 v = *(const uint2*)(Wsrc + e0);
        u32 a = (u32)f2bf(bf2f((u16)(v.x & 0xffffu)) * sc)
              | ((u32)f2bf(bf2f((u16)(v.x >> 16)) * sc) << 16);
        u32 b = (u32)f2bf(bf2f((u16)(v.y & 0xffffu)) * sc)
              | ((u32)f2bf(bf2f((u16)(v.y >> 16)) * sc) << 16);
        *(uint2*)(Wdst + e0) = (uint2){a, b};
        return;
    }
    if (bid >= gb) {
        int i = (bid - gb) * 256 + tid;
        if (i < n4) {
            int4 v = *(const int4*)(e + (size_t)i * 4);
            float4 o;
            o.x = (float)v.x; o.y = (float)v.y; o.z = (float)v.z; o.w = (float)v.w;
            *(float4*)(eout + (size_t)i * 4) = o;
        }
        return;
    }
    const int lane = tid & 63;
    const int wave = tid >> 6;
    const int row0 = (bid * 4 + wave) * 16;
    if (row0 >= M) return;
    const int col  = lane & 15;
    const int quad = lane >> 4;

    f32x4 c1[4];
#pragma unroll
    for (int jt = 0; jt < 4; ++jt) c1[jt] = (f32x4){0.f, 0.f, 0.f, 0.f};
    {
        const u16* xrow = X  + (size_t)(row0 + col) * 64 + quad * 8;
        const u16* wrow = pw + (size_t)col * 64 + quad * 8;
#pragma unroll
        for (int kc = 0; kc < 64; kc += 32) {
            short8 a = *(const short8*)(xrow + kc);
#pragma unroll
            for (int jt = 0; jt < 4; ++jt) {
                short8 b = *(const short8*)(wrow + (size_t)jt * 16 * 64 + kc);
                c1[jt] = MFMA16(a, b, c1[jt], 0, 0, 0);
            }
        }
    }
#pragma unroll
    for (int jt = 0; jt < 4; ++jt) {
        float bias = bf2f(pb[jt * 16 + col]);
#pragma unroll
        for (int r = 0; r < 4; ++r) {
            float v = fmaxf(c1[jt][r] + bias, 0.f);
            XP[(size_t)(row0 + quad * 4 + r) * 64 + jt * 16 + col] = f2bf(v);
        }
    }
}

// ===========================================================================
// LSTM v17: THIN WAVES. 512-thread block, 8 waves = {4 dim-slices} x
// {2 node-groups}, 32 nodes/block. Each wave = 1 stream, 4 gate tiles,
// ~110 regs -> LDS (41KB -> 3 blocks/CU) gives 24 waves/CU = 6 waves/SIMD,
// double every prior config. r4(1str@3blk)=93.9 == r8(2str@2blk)=93.3 proved
// the wall is latency-structure; the lever is independently-progressing
// waves per SIMD, which only lighter waves can raise. Drainless core kept:
// xs = 2 phases x 4 steps x 32 nodes; gload_lds refills (zero VGPR) at
// t=4/8, vmcnt(0) at t=7/11; in-loop barriers lgkmcnt-only.
// Staging: wave w stages step w (k=0..3); refills: wave(ng,wd) stages step
// {8,12}+wd rows [2ng*8, 2ng*8+16).
// ===========================================================================

#define NONLIN(ACC, CST, HW0, HW1)                                             \
    {                                                                          \
        float hv[4];                                                           \
        _Pragma("unroll") for (int r = 0; r < 4; ++r) {                        \
            float iv = ACC[0][r], fv = ACC[1][r], gv = ACC[2][r], ov = ACC[3][r]; \
            float e_i = __builtin_amdgcn_exp2f(-iv);                           \
            float e_f = __builtin_amdgcn_exp2f(-fv);                           \
            float e_g = __builtin_amdgcn_exp2f(gv);                            \
            float af  = 1.0f + e_f;                                            \
            float P   = (1.0f + e_i) * (1.0f + e_g);                           \
            float tt  = __builtin_fmaf(e_g, KS2, -KS2);                        \
            float num = __builtin_fmaf(tt, af, CST[r] * P);                    \
            float cn  = num * __builtin_amdgcn_rcpf(af * P);                   \
            CST[r] = cn;                                                       \
            float e_c = __builtin_amdgcn_exp2f(cn);                            \
            float e_o = __builtin_amdgcn_exp2f(-ov);                           \
            float roc = __builtin_amdgcn_rcpf((1.0f + e_o) * (1.0f + e_c));    \
            hv[r] = (e_c - 1.0f) * roc;                                        \
        }                                                                      \
        HW0 = pack_bf2(hv[0], hv[1]);                                          \
        HW1 = pack_bf2(hv[2], hv[3]);                                          \
    }

#define LSTMT_PROLOGUE                                                         \
    const int tid  = threadIdx.x;                                              \
    const int lane = tid & 63;                                                 \
    const int w    = tid >> 6;           /* 0..7 */                            \
    const int wd   = w & 3;              /* dim-slice */                       \
    const int ng   = w >> 2;             /* node-group */                      \
    const int col  = lane & 15;                                                \
    const int quad = lane >> 4;                                                \
    const int node0 = blockIdx.x * 32;                                         \
    if (node0 >= N) return;                                                    \
    const int nd  = node0 + ng * 16 + col;                                     \
    const bool act = nd < N;                                                   \
    const int ndc  = act ? nd : (N - 1);                                       \
    if (tid < 256) {                                                           \
        int j = tid;                                                           \
        float sc = (j >= 128 && j < 192) ? KS2 : KS1;                          \
        lds_b[j] = (bf2f(bih[j]) + bf2f(bhh[j])) * sc;                         \
    }                                                                          \
    const int rlo = lane >> 3;                 /* row-within-8 */              \
    const u16* gch = xp + (((lane & 7) ^ rlo) << 3);  /* pre-swizzled chunk */ \
    int i2k[2], i3k[2];                                                        \
    _Pragma("unroll") for (int k = 0; k < 4; ++k) {   /* stage step w */       \
        int rn = node0 + k * 8 + rlo; if (rn >= N) rn = N - 1;                 \
        int i0 = src[(size_t)rn * 16 + w];                                     \
        gload_lds16(gch + (size_t)i0 * 64, xs + w * 2048 + k * 512);           \
    }                                                                          \
    _Pragma("unroll") for (int k2 = 0; k2 < 2; ++k2) {                         \
        int k = 2 * ng + k2;                                                   \
        int rn = node0 + k * 8 + rlo; if (rn >= N) rn = N - 1;                 \
        const int* sp = src + (size_t)rn * 16;                                 \
        i2k[k2] = sp[8 + wd];                                                  \
        i3k[k2] = sp[12 + wd];                                                 \
    }                                                                          \
    short8 wf[8], hf[8];                                                       \
    _Pragma("unroll") for (int g = 0; g < 4; ++g) {                            \
        int jt = wd + 4 * g;                                                   \
        const u16* wi = wihs + (size_t)(jt * 16 + col) * 64 + quad * 8;        \
        const u16* wh = whhs + (size_t)(jt * 16 + col) * 64 + quad * 8;        \
        wf[g * 2 + 0] = *(const short8*)(wi);                                  \
        wf[g * 2 + 1] = *(const short8*)(wi + 32);                             \
        hf[g * 2 + 0] = *(const short8*)(wh);                                  \
        hf[g * 2 + 1] = *(const short8*)(wh + 32);                             \
    }                                                                          \
    __syncthreads();                                                           \
    const int q0 = quad ^ (col & 7);                                           \
    const int myrow = ng * 16 + col;

#define LSTMT_CORE_LOOP                                                        \
    short8 hb0 = (short8){0,0,0,0,0,0,0,0};                                    \
    short8 hb1 = hb0;                                                          \
    float cA[4];                                                               \
    _Pragma("unroll") for (int i = 0; i < 4; ++i) cA[i] = 0.f;                 \
    _Pragma("unroll 1") for (int t = 0; t < 16; ++t) {                         \
        if (t == 7 || t == 11)                                                 \
            asm volatile("s_waitcnt vmcnt(0)" ::: "memory");                   \
        const u16* pS = xs + ((((t >> 2) & 1) * 4 + (t & 3)) * 2048);          \
        const u16* pA = pS + myrow * 64;                                       \
        short8 xb0 = *(const short8*)(pA + q0 * 8);                            \
        short8 xb1 = *(const short8*)(pA + ((q0 ^ 4) << 3));                   \
        if (t == 4) {   /* refill steps 8..11 into slots 0..3 */               \
            _Pragma("unroll") for (int k2 = 0; k2 < 2; ++k2)                   \
                gload_lds16(gch + (size_t)i2k[k2] * 64,                        \
                            xs + wd * 2048 + (2 * ng + k2) * 512);             \
        }                                                                      \
        if (t == 8) {   /* refill steps 12..15 into slots 4..7 */              \
            _Pragma("unroll") for (int k2 = 0; k2 < 2; ++k2)                   \
                gload_lds16(gch + (size_t)i3k[k2] * 64,                        \
                            xs + (4 + wd) * 2048 + (2 * ng + k2) * 512);       \
        }                                                                      \
        f32x4 acc[4];                                                          \
        _Pragma("unroll") for (int g = 0; g < 4; ++g) {                        \
            f32x4 bc = *(const f32x4*)(lds_b + (wd + 4 * g) * 16 + quad * 4);  \
            acc[g] = MFMA16(wf[g * 2 + 0], xb0, bc, 0, 0, 0);                  \
            acc[g] = MFMA16(wf[g * 2 + 1], xb1, acc[g], 0, 0, 0);              \
        }                                                                      \
        if (t > 0) {                                                           \
            _Pragma("unroll") for (int g = 0; g < 4; ++g) {                    \
                acc[g] = MFMA16(hf[g * 2 + 0], hb0, acc[g], 0, 0, 0);          \
                acc[g] = MFMA16(hf[g * 2 + 1], hb1, acc[g], 0, 0, 0);          \
            }                                                                  \
        }                                                                      \
        u32 hw0, hw1;                                                          \
        NONLIN(acc, cA, hw0, hw1)                                              \
        u16* hbuf = lds_h[t & 1];                                              \
        xwrite(hbuf, 64, myrow, quad, wd, hw0, hw1);                           \
        barrier_lds();                                                         \
        hb0 = xread(hbuf, 64, myrow, quad, 0);                                 \
        hb1 = xread(hbuf, 64, myrow, quad, 1);                                 \
    }

// ---------------------------------------------------------------------------
// lstm_mid: layer-1 LSTM + fused Y1 + xp2
// ---------------------------------------------------------------------------
__global__ __launch_bounds__(512, 6) void lstm_mid(
    const u16* __restrict__ xp, const int* __restrict__ src,
    const u16* __restrict__ wihs, const u16* __restrict__ whhs,
    const u16* __restrict__ bih, const u16* __restrict__ bhh,
    const u16* __restrict__ X,                                   // root x [N,64]
    const u16* __restrict__ llw, const u16* __restrict__ llb,
    const u16* __restrict__ lrw,
    const u16* __restrict__ pw, const u16* __restrict__ pb,
    u16* __restrict__ Y1, u16* __restrict__ XP2, int N)
{
    __shared__ u16 xs[8 * 2048];        // 32KB staged x (2 phases x 4 steps x 32 nodes)
    __shared__ float lds_b[256];        // 1KB scaled bias'
    __shared__ u16 lds_h[2][32 * 64];   // 8KB h double buffer
    u16* bufY = xs;                     // epilogue alias (xs dead after loop)

    LSTMT_PROLOGUE
    LSTMT_CORE_LOOP

    // ---- epilogue: hb0/hb1 = final H B-frags ----
    {
        const u16* wr  = llw + (size_t)(wd * 16 + col) * 64 + quad * 8;
        short8 ll0 = *(const short8*)wr, ll1 = *(const short8*)(wr + 32);
        const u16* wr2 = lrw + (size_t)(wd * 16 + col) * 64 + quad * 8;
        short8 lr0 = *(const short8*)wr2, lr1 = *(const short8*)(wr2 + 32);
        f32x4 bY = bias4(llb + wd * 16 + quad * 4);

        const u16* xr = X + (size_t)ndc * 64 + quad * 8;
        short8 rx0 = *(const short8*)xr, rx1 = *(const short8*)(xr + 32);

        f32x4 aA = MFMA16(ll0, hb0, bY, 0, 0, 0);
        aA = MFMA16(ll1, hb1, aA, 0, 0, 0);
        aA = MFMA16(lr0, rx0, aA, 0, 0, 0);
        aA = MFMA16(lr1, rx1, aA, 0, 0, 0);

        u32 y0 = pack_relu(aA[0], aA[1]), y1 = pack_relu(aA[2], aA[3]);
        if (act) *(uint2*)(Y1 + (size_t)nd * 64 + wd * 16 + quad * 4) = (uint2){y0, y1};
        xwrite(bufY, 64, myrow, quad, wd, y0, y1);
        __syncthreads();

        const u16* wp = pw + (size_t)(wd * 16 + col) * 64 + quad * 8;
        short8 p0 = *(const short8*)wp, p1 = *(const short8*)(wp + 32);
        f32x4 bp = bias4(pb + wd * 16 + quad * 4);

        short8 yb0 = xread(bufY, 64, myrow, quad, 0);
        short8 yb1 = xread(bufY, 64, myrow, quad, 1);

        f32x4 a2 = MFMA16(p0, yb0, bp, 0, 0, 0);
        a2 = MFMA16(p1, yb1, a2, 0, 0, 0);

        if (act) *(uint2*)(XP2 + (size_t)nd * 64 + wd * 16 + quad * 4) =
            (uint2){pack_relu(a2[0], a2[1]), pack_relu(a2[2], a2[3])};
    }
}

// ---------------------------------------------------------------------------
// lstm_post: layer-2 LSTM + fused Y2[128] -> T1[192] -> T2[64] -> out[64] f32
// ---------------------------------------------------------------------------
__global__ __launch_bounds__(512, 6) void lstm_post(
    const u16* __restrict__ xp, const int* __restrict__ src,
    const u16* __restrict__ wihs, const u16* __restrict__ whhs,
    const u16* __restrict__ bih, const u16* __restrict__ bhh,
    const u16* __restrict__ Y1,                                  // [N,64]
    const u16* __restrict__ llw2, const u16* __restrict__ llb2,
    const u16* __restrict__ lrw2,                                // [128,64],[128],[128,64]
    const u16* __restrict__ w1m, const u16* __restrict__ b1m,    // [192,128],[192]
    const u16* __restrict__ w2m, const u16* __restrict__ b2m,    // [64,192],[64]
    const u16* __restrict__ w3m, const u16* __restrict__ b3m,    // [64,64],[64]
    float* __restrict__ outp, int N)
{
    __shared__ u16 xs[8 * 2048];        // 32KB staged x
    __shared__ float lds_b[256];        // 1KB
    __shared__ u16 lds_h[2][32 * 64];   // 8KB
    u16* bufA = (u16*)lds_h;            // 8KB: Y2 exchange (32x128), then T2 @64
    u16* bufB = xs;                     // 12KB of xs: T1 exchange (32x192)

    LSTMT_PROLOGUE
    LSTMT_CORE_LOOP

    // ---- epilogue ----
    {
        barrier_lds();   // bufA aliases lds_h: ensure all waves' final hb reads done

        const u16* yr = Y1 + (size_t)ndc * 64 + quad * 8;
        short8 ry0 = *(const short8*)yr, ry1 = *(const short8*)(yr + 32);

        // Y2 tiles jt = 2wd, 2wd+1 (this wave's node-group)
#pragma unroll
        for (int ti = 0; ti < 2; ++ti) {
            int jt = 2 * wd + ti;
            const u16* wr = llw2 + (size_t)(jt * 16 + col) * 64 + quad * 8;
            short8 l0 = *(const short8*)wr, l1 = *(const short8*)(wr + 32);
            const u16* wr2 = lrw2 + (size_t)(jt * 16 + col) * 64 + quad * 8;
            short8 r0 = *(const short8*)wr2, r1 = *(const short8*)(wr2 + 32);
            f32x4 b0 = bias4(llb2 + jt * 16 + quad * 4);
            f32x4 aA = MFMA16(l0, hb0, b0, 0, 0, 0);
            aA = MFMA16(l1, hb1, aA, 0, 0, 0);
            aA = MFMA16(r0, ry0, aA, 0, 0, 0);
            aA = MFMA16(r1, ry1, aA, 0, 0, 0);
            xwrite(bufA, 128, myrow, quad, jt, pack_relu(aA[0], aA[1]), pack_relu(aA[2], aA[3]));
        }
        __syncthreads();

        short8 y2[4];
#pragma unroll
        for (int kc = 0; kc < 4; ++kc) y2[kc] = xread(bufA, 128, myrow, quad, kc);

        // T1 tiles jt = 3wd..3wd+2, K=128
#pragma unroll
        for (int ti = 0; ti < 3; ++ti) {
            int jt = 3 * wd + ti;
            const u16* wr = w1m + (size_t)(jt * 16 + col) * 128 + quad * 8;
            short8 wk[4];
#pragma unroll
            for (int kc = 0; kc < 4; ++kc) wk[kc] = *(const short8*)(wr + kc * 32);
            f32x4 b1v = bias4(b1m + jt * 16 + quad * 4);
            f32x4 aA = b1v;
#pragma unroll
            for (int kc = 0; kc < 4; ++kc) aA = MFMA16(wk[kc], y2[kc], aA, 0, 0, 0);
            xwrite(bufB, 192, myrow, quad, jt, pack_relu(aA[0], aA[1]), pack_relu(aA[2], aA[3]));
        }
        __syncthreads();

        short8 t1[6];
#pragma unroll
        for (int kc = 0; kc < 6; ++kc) t1[kc] = xread(bufB, 192, myrow, quad, kc);

        // T2 tile jt=wd, K=192 (bufA reuse @ stride 64 — Y2 reads completed pre-barrier)
        {
            const u16* wr = w2m + (size_t)(wd * 16 + col) * 192 + quad * 8;
            f32x4 b2v = bias4(b2m + wd * 16 + quad * 4);
            f32x4 aA = b2v;
#pragma unroll
            for (int kc = 0; kc < 6; ++kc) {
                short8 wk = *(const short8*)(wr + kc * 32);
                aA = MFMA16(wk, t1[kc], aA, 0, 0, 0);
            }
            xwrite(bufA, 64, myrow, quad, wd, pack_relu(aA[0], aA[1]), pack_relu(aA[2], aA[3]));
        }
        __syncthreads();

        short8 t20 = xread(bufA, 64, myrow, quad, 0);
        short8 t21 = xread(bufA, 64, myrow, quad, 1);
        // out tile jt=wd, K=64, f32 store
        {
            const u16* wr = w3m + (size_t)(wd * 16 + col) * 64 + quad * 8;
            short8 l0 = *(const short8*)wr, l1 = *(const short8*)(wr + 32);
            f32x4 b3v = bias4(b3m + wd * 16 + quad * 4);
            f32x4 aA = MFMA16(l0, t20, b3v, 0, 0, 0);
            aA = MFMA16(l1, t21, aA, 0, 0, 0);
            if (act) {
                float4 oA;
                oA.x = fmaxf(aA[0], 0.f); oA.y = fmaxf(aA[1], 0.f);
                oA.z = fmaxf(aA[2], 0.f); oA.w = fmaxf(aA[3], 0.f);
                *(float4*)(outp + (size_t)nd * 64 + wd * 16 + quad * 4) = oA;
            }
        }
    }
}

// ---------------------------------------------------------------------------
extern "C" void kernel_launch(void* const* d_in, const int* in_sizes, int n_in,
                              void* d_out, int out_size, void* d_ws, size_t ws_size,
                              hipStream_t stream)
{
    const u16* x       = (const u16*)d_in[0];
    const int* edge    = (const int*)d_in[1];
    const u16* p1_pw   = (const u16*)d_in[3];
    const u16* p1_pb   = (const u16*)d_in[4];
    const u16* p1_wih  = (const u16*)d_in[5];
    const u16* p1_whh  = (const u16*)d_in[6];
    const u16* p1_bih  = (const u16*)d_in[7];
    const u16* p1_bhh  = (const u16*)d_in[8];
    const u16* p1_llw  = (const u16*)d_in[9];
    const u16* p1_llb  = (const u16*)d_in[10];
    const u16* p1_lrw  = (const u16*)d_in[11];
    const u16* p2_pw   = (const u16*)d_in[12];
    const u16* p2_pb   = (const u16*)d_in[13];
    const u16* p2_wih  = (const u16*)d_in[14];
    const u16* p2_whh  = (const u16*)d_in[15];
    const u16* p2_bih  = (const u16*)d_in[16];
    const u16* p2_bhh  = (const u16*)d_in[17];
    const u16* p2_llw  = (const u16*)d_in[18];
    const u16* p2_llb  = (const u16*)d_in[19];
    const u16* p2_lrw  = (const u16*)d_in[20];
    const u16* lin1w   = (const u16*)d_in[21];
    const u16* lin1b   = (const u16*)d_in[22];
    const u16* lin2w   = (const u16*)d_in[23];
    const u16* lin2b   = (const u16*)d_in[24];
    const u16* lin3w   = (const u16*)d_in[25];
    const u16* lin3b   = (const u16*)d_in[26];
    (void)n_in; (void)ws_size;

    const int N  = in_sizes[0] / 64;     // 50000
    const int E2 = in_sizes[1];          // 1600000
    const int* srcIdx = edge;

    // workspace: scaled weights 128KB @0; xp1 @1MB; xp2 @8MB; Y1 @15MB
    char* w = (char*)d_ws;
    u16* wss   = (u16*)(w);
    u16* xp1   = (u16*)(w + 1u  * 1024 * 1024);
    u16* xp2   = (u16*)(w + 8u  * 1024 * 1024);
    u16* bufY1 = (u16*)(w + 15u * 1024 * 1024);
    u16* wih1s = wss;
    u16* whh1s = wss + 16384;
    u16* wih2s = wss + 32768;
    u16* whh2s = wss + 49152;

    float* out_h    = (float*)d_out;
    float* out_edge = (float*)d_out + (size_t)N * 64;
    (void)out_size;

    const int gb  = (N + 63) / 64;       // 782 (xp1 GEMM blocks)
    const int gbl = (N + 31) / 32;       // 1563 (lstm blocks, 32 nodes each)
    const int n4 = E2 / 4;
    const int eb = (n4 + 255) / 256;     // 1563

    hipLaunchKernelGGL(k_pre, dim3(gb + eb + 64), dim3(256), 0, stream,
                       x, p1_pw, p1_pb, xp1, N, gb,
                       edge, out_edge, n4, eb,
                       p1_wih, p1_whh, p2_wih, p2_whh, wss);
    hipLaunchKernelGGL(lstm_mid, dim3(gbl), dim3(512), 0, stream,
                       xp1, srcIdx, wih1s, whh1s, p1_bih, p1_bhh,
                       x, p1_llw, p1_llb, p1_lrw, p2_pw, p2_pb, bufY1, xp2, N);
    hipLaunchKernelGGL(lstm_post, dim3(gbl), dim3(512), 0, stream,
                       xp2, srcIdx, wih2s, whh2s, p2_bih, p2_bhh,
                       bufY1, p2_llw, p2_llb, p2_lrw,
                       lin1w, lin1b, lin2w, lin2b, lin3w, lin3b, out_h, N);
}

// Round 10
// 287.892 us; speedup vs baseline: 2.3643x; 2.3643x over previous
//
#include <hip/hip_runtime.h>
#include <hip/hip_bf16.h>

typedef unsigned short u16;
typedef unsigned int u32;
typedef __attribute__((ext_vector_type(8))) short short8;    // 8 bf16 MFMA A/B frag
typedef __attribute__((ext_vector_type(4))) float f32x4;

#define KS1 1.44269504f   // log2(e)
#define KS2 2.88539008f   // 2*log2(e)

__device__ __forceinline__ float bf2f(u16 u) {
    union { u32 i; float f; } v; v.i = ((u32)u) << 16; return v.f;
}
__device__ __forceinline__ u16 f2bf(float f) {            // RNE
    union { float f; u32 i; } v; v.f = f;
    u32 r = v.i + 0x7fffu + ((v.i >> 16) & 1u);
    return (u16)(r >> 16);
}
// pack two f32 -> two bf16 (truncation) in ONE v_perm (h state only)
__device__ __forceinline__ u32 pack_bf2(float lo, float hi) {
    return __builtin_amdgcn_perm(__float_as_uint(hi), __float_as_uint(lo), 0x07060302u);
}
// relu + RNE pack (epilogue intermediates)
__device__ __forceinline__ u32 pack_relu(float a, float b) {
    return (u32)f2bf(fmaxf(a, 0.f)) | ((u32)f2bf(fmaxf(b, 0.f)) << 16);
}
__device__ __forceinline__ f32x4 bias4(const u16* b) {
    uint2 u = *(const uint2*)b;
    f32x4 r;
    r[0] = bf2f((u16)(u.x & 0xffffu)); r[1] = bf2f((u16)(u.x >> 16));
    r[2] = bf2f((u16)(u.y & 0xffffu)); r[3] = bf2f((u16)(u.y >> 16));
    return r;
}
// LDS-only barrier: lgkmcnt(0)+s_barrier. Does NOT drain vmcnt, so the
// global_load_lds refills stay in flight across step barriers.
__device__ __forceinline__ void barrier_lds() {
    asm volatile("s_waitcnt lgkmcnt(0)" ::: "memory");
    __builtin_amdgcn_s_barrier();
}
// direct global->LDS 16B copy: lane writes at ldsbase + lane*16 (HW rule),
// so the XOR-swizzle is applied on the per-lane GLOBAL source instead.
__device__ __forceinline__ void gload_lds16(const u16* g, u16* l) {
    __builtin_amdgcn_global_load_lds(
        (const __attribute__((address_space(1))) u32*)(const void*)g,
        (__attribute__((address_space(3))) u32*)(void*)l, 16, 0, 0);
}
// XOR-swizzled exchange buffer (proven bank-free: <=2-way per 16-lane quarter).
__device__ __forceinline__ void xwrite(u16* buf, int D2, int row, int quad, int jt, u32 w0, u32 w1) {
    int ch = jt * 2 + (quad >> 1);
    *(uint2*)(buf + row * D2 + ((ch ^ (row & 7)) << 3) + ((quad & 1) << 2)) = (uint2){w0, w1};
}
__device__ __forceinline__ short8 xread(const u16* buf, int D2, int row, int quad, int kc) {
    return *(const short8*)(buf + row * D2 + (((kc * 4 + quad) ^ (row & 7)) << 3));
}
#define MFMA16 __builtin_amdgcn_mfma_f32_16x16x32_bf16

// ---------------------------------------------------------------------------
// k_pre: [0,gb) xp1 GEMM; [gb,gb+64) scaled weight copy.
// (edge cast moved into lstm_mid's grid -- hides under the latency-bound LSTM)
// ---------------------------------------------------------------------------
__global__ __launch_bounds__(256) void k_pre(
    const u16* __restrict__ X, const u16* __restrict__ pw, const u16* __restrict__ pb,
    u16* __restrict__ XP, int M, int gb,
    const u16* __restrict__ w1i, const u16* __restrict__ w1h,
    const u16* __restrict__ w2i, const u16* __restrict__ w2h,
    u16* __restrict__ wss)
{
    const int bid = blockIdx.x;
    const int tid = threadIdx.x;
    if (bid >= gb) {
        int wb = bid - gb;                 // 0..63
        int mi = wb >> 4;
        const u16* Wsrc = (mi == 0) ? w1i : (mi == 1) ? w1h : (mi == 2) ? w2i : w2h;
        u16* Wdst = wss + (size_t)mi * 16384;
        int e0 = (wb & 15) * 1024 + tid * 4;
        int row = e0 >> 6;
        float sc = (row >= 128 && row < 192) ? KS2 : KS1;
        uint2 v = *(const uint2*)(Wsrc + e0);
        u32 a = (u32)f2bf(bf2f((u16)(v.x & 0xffffu)) * sc)
              | ((u32)f2bf(bf2f((u16)(v.x >> 16)) * sc) << 16);
        u32 b = (u32)f2bf(bf2f((u16)(v.y & 0xffffu)) * sc)
              | ((u32)f2bf(bf2f((u16)(v.y >> 16)) * sc) << 16);
        *(uint2*)(Wdst + e0) = (uint2){a, b};
        return;
    }
    const int lane = tid & 63;
    const int wave = tid >> 6;
    const int row0 = (bid * 4 + wave) * 16;
    if (row0 >= M) return;
    const int col  = lane & 15;
    const int quad = lane >> 4;

    f32x4 c1[4];
#pragma unroll
    for (int jt = 0; jt < 4; ++jt) c1[jt] = (f32x4){0.f, 0.f, 0.f, 0.f};
    {
        const u16* xrow = X  + (size_t)(row0 + col) * 64 + quad * 8;
        const u16* wrow = pw + (size_t)col * 64 + quad * 8;
#pragma unroll
        for (int kc = 0; kc < 64; kc += 32) {
            short8 a = *(const short8*)(xrow + kc);
#pragma unroll
            for (int jt = 0; jt < 4; ++jt) {
                short8 b = *(const short8*)(wrow + (size_t)jt * 16 * 64 + kc);
                c1[jt] = MFMA16(a, b, c1[jt], 0, 0, 0);
            }
        }
    }
#pragma unroll
    for (int jt = 0; jt < 4; ++jt) {
        float bias = bf2f(pb[jt * 16 + col]);
#pragma unroll
        for (int r = 0; r < 4; ++r) {
            float v = fmaxf(c1[jt][r] + bias, 0.f);
            XP[(size_t)(row0 + quad * 4 + r) * 64 + jt * 16 + col] = f2bf(v);
        }
    }
}

// ===========================================================================
// LSTM v18 = r8's verified v16 (drainless 2-stream, 93.3us) + bc-HOIST.
// The bias C-operand was re-read from LDS (4x ds_read_b128) after EVERY
// barrier, feeding the first MFMA -> a ~120cy critical-path link per step
// that the compiler cannot hoist across the asm-volatile barrier. Hoisted
// to 16 VGPRs (84 -> ~100, budget 170: safe, unlike r5's +64 spill).
// Also: edge cast folded into this kernel's grid tail (pure-BW blocks that
// hide under the latency-bound LSTM blocks instead of serializing k_pre).
// ===========================================================================

#define NONLIN(ACC, CST, HW0, HW1)                                             \
    {                                                                          \
        float hv[4];                                                           \
        _Pragma("unroll") for (int r = 0; r < 4; ++r) {                        \
            float iv = ACC[0][r], fv = ACC[1][r], gv = ACC[2][r], ov = ACC[3][r]; \
            float e_i = __builtin_amdgcn_exp2f(-iv);                           \
            float e_f = __builtin_amdgcn_exp2f(-fv);                           \
            float e_g = __builtin_amdgcn_exp2f(gv);                            \
            float af  = 1.0f + e_f;                                            \
            float P   = (1.0f + e_i) * (1.0f + e_g);                           \
            float tt  = __builtin_fmaf(e_g, KS2, -KS2);                        \
            float num = __builtin_fmaf(tt, af, CST[r] * P);                    \
            float cn  = num * __builtin_amdgcn_rcpf(af * P);                   \
            CST[r] = cn;                                                       \
            float e_c = __builtin_amdgcn_exp2f(cn);                            \
            float e_o = __builtin_amdgcn_exp2f(-ov);                           \
            float roc = __builtin_amdgcn_rcpf((1.0f + e_o) * (1.0f + e_c));    \
            hv[r] = (e_c - 1.0f) * roc;                                        \
        }                                                                      \
        HW0 = pack_bf2(hv[0], hv[1]);                                          \
        HW1 = pack_bf2(hv[2], hv[3]);                                          \
    }

#define LSTM2G_PROLOGUE                                                        \
    const int tid  = threadIdx.x;                                              \
    const int lane = tid & 63;                                                 \
    const int w    = tid >> 6;                                                 \
    const int col  = lane & 15;                                                \
    const int quad = lane >> 4;                                                \
    const int node0 = blockIdx.x * 32;                                         \
    if (node0 >= N) return;                                                    \
    const bool actB = (node0 + 32 <= N);                                       \
    const int nodeA = node0 + col;                                             \
    const int nodeB = actB ? (node0 + 16 + col) : nodeA;                       \
    {                                                                          \
        int j = tid;                                                           \
        float sc = (j >= 128 && j < 192) ? KS2 : KS1;                          \
        lds_b[j] = (bf2f(bih[j]) + bf2f(bhh[j])) * sc;                         \
    }                                                                          \
    const int rlo = lane >> 3;                 /* row-within-8 */              \
    const u16* gch = xp + (((lane & 7) ^ rlo) << 3);  /* pre-swizzled chunk */ \
    int i2k[4], i3k[4];                                                        \
    _Pragma("unroll") for (int k = 0; k < 4; ++k) {                            \
        int rn = node0 + k * 8 + rlo; if (rn >= N) rn = N - 1;                 \
        const int* sp = src + (size_t)rn * 16;                                 \
        int i0 = sp[w], i1 = sp[4 + w];                                        \
        i2k[k] = sp[8 + w]; i3k[k] = sp[12 + w];                               \
        gload_lds16(gch + (size_t)i0 * 64, xs + w * 2048 + k * 512);           \
        gload_lds16(gch + (size_t)i1 * 64, xs + (4 + w) * 2048 + k * 512);     \
    }                                                                          \
    short8 wf[8], hf[8];                                                       \
    _Pragma("unroll") for (int g = 0; g < 4; ++g) {                            \
        int jt = w + 4 * g;                                                    \
        const u16* wi = wihs + (size_t)(jt * 16 + col) * 64 + quad * 8;        \
        const u16* wh = whhs + (size_t)(jt * 16 + col) * 64 + quad * 8;        \
        wf[g * 2 + 0] = *(const short8*)(wi);                                  \
        wf[g * 2 + 1] = *(const short8*)(wi + 32);                             \
        hf[g * 2 + 0] = *(const short8*)(wh);                                  \
        hf[g * 2 + 1] = *(const short8*)(wh + 32);                             \
    }                                                                          \
    __syncthreads();                                                           \
    f32x4 bch[4];                                                              \
    _Pragma("unroll") for (int g = 0; g < 4; ++g)                              \
        bch[g] = *(const f32x4*)(lds_b + (w + 4 * g) * 16 + quad * 4);         \
    const int q0 = quad ^ (col & 7);

#define LSTM2G_CORE_LOOP                                                       \
    short8 z8 = (short8){0,0,0,0,0,0,0,0};                                     \
    short8 hbA0 = z8, hbA1 = z8, hbB0 = z8, hbB1 = z8;                         \
    float cA[4], cB[4];                                                        \
    _Pragma("unroll") for (int i = 0; i < 4; ++i) { cA[i] = 0.f; cB[i] = 0.f; }\
    _Pragma("unroll 1") for (int t = 0; t < 16; ++t) {                         \
        if (t == 7 || t == 11)                                                 \
            asm volatile("s_waitcnt vmcnt(0)" ::: "memory");                   \
        const u16* pS = xs + ((((t >> 2) & 1) * 4 + (t & 3)) * 2048);          \
        const u16* pA = pS + col * 64;                                         \
        short8 xbA0 = *(const short8*)(pA + q0 * 8);                           \
        short8 xbA1 = *(const short8*)(pA + ((q0 ^ 4) << 3));                  \
        const u16* pB = pS + (col + 16) * 64;                                  \
        short8 xbB0 = *(const short8*)(pB + q0 * 8);                           \
        short8 xbB1 = *(const short8*)(pB + ((q0 ^ 4) << 3));                  \
        if (t == 4) {   /* refill steps 8..11 into buffer0 (slot w) */         \
            _Pragma("unroll") for (int k = 0; k < 4; ++k)                      \
                gload_lds16(gch + (size_t)i2k[k] * 64, xs + w * 2048 + k * 512); \
        }                                                                      \
        if (t == 8) {   /* refill steps 12..15 into buffer1 (slot 4+w) */      \
            _Pragma("unroll") for (int k = 0; k < 4; ++k)                      \
                gload_lds16(gch + (size_t)i3k[k] * 64, xs + (4 + w) * 2048 + k * 512); \
        }                                                                      \
        f32x4 accA[4], accB[4];                                                \
        _Pragma("unroll") for (int g = 0; g < 4; ++g) {                        \
            accA[g] = MFMA16(wf[g * 2 + 0], xbA0, bch[g], 0, 0, 0);            \
            accB[g] = MFMA16(wf[g * 2 + 0], xbB0, bch[g], 0, 0, 0);            \
            accA[g] = MFMA16(wf[g * 2 + 1], xbA1, accA[g], 0, 0, 0);           \
            accB[g] = MFMA16(wf[g * 2 + 1], xbB1, accB[g], 0, 0, 0);           \
        }                                                                      \
        if (t > 0) {                                                           \
            _Pragma("unroll") for (int g = 0; g < 4; ++g) {                    \
                accA[g] = MFMA16(hf[g * 2 + 0], hbA0, accA[g], 0, 0, 0);       \
                accB[g] = MFMA16(hf[g * 2 + 0], hbB0, accB[g], 0, 0, 0);       \
                accA[g] = MFMA16(hf[g * 2 + 1], hbA1, accA[g], 0, 0, 0);       \
                accB[g] = MFMA16(hf[g * 2 + 1], hbB1, accB[g], 0, 0, 0);       \
            }                                                                  \
        }                                                                      \
        u32 hwA0, hwA1, hwB0, hwB1;                                            \
        NONLIN(accA, cA, hwA0, hwA1)                                           \
        NONLIN(accB, cB, hwB0, hwB1)                                           \
        u16* hbuf = lds_h[t & 1];                                              \
        xwrite(hbuf, 64, col,      quad, w, hwA0, hwA1);                       \
        xwrite(hbuf, 64, col + 16, quad, w, hwB0, hwB1);                       \
        barrier_lds();                                                         \
        hbA0 = xread(hbuf, 64, col,      quad, 0);                             \
        hbA1 = xread(hbuf, 64, col,      quad, 1);                             \
        hbB0 = xread(hbuf, 64, col + 16, quad, 0);                             \
        hbB1 = xread(hbuf, 64, col + 16, quad, 1);                             \
    }

// ---------------------------------------------------------------------------
// lstm_mid: layer-1 LSTM + fused Y1 + xp2; tail blocks do the edge cast
// ---------------------------------------------------------------------------
__global__ __launch_bounds__(256, 3) void lstm_mid(
    const u16* __restrict__ xp, const int* __restrict__ src,
    const u16* __restrict__ wihs, const u16* __restrict__ whhs,
    const u16* __restrict__ bih, const u16* __restrict__ bhh,
    const u16* __restrict__ X,                                   // root x [N,64]
    const u16* __restrict__ llw, const u16* __restrict__ llb,
    const u16* __restrict__ lrw,
    const u16* __restrict__ pw, const u16* __restrict__ pb,
    u16* __restrict__ Y1, u16* __restrict__ XP2, int N,
    float* __restrict__ eout, int n4, int nlstm)
{
    __shared__ u16 xs[8 * 2048];        // 32KB staged x (2 phases x 4 steps x 32 nodes)
    __shared__ float lds_b[256];        // 1KB scaled bias'
    __shared__ u16 lds_h[2][32 * 64];   // 8KB h double buffer
    u16* bufY = xs;                     // epilogue alias (xs dead after loop)

    if ((int)blockIdx.x >= nlstm) {     // edge-cast tail blocks (pure BW)
        int i = ((int)blockIdx.x - nlstm) * 256 + (int)threadIdx.x;
        if (i < n4) {
            int4 v = *(const int4*)(src + (size_t)i * 4);
            float4 o;
            o.x = (float)v.x; o.y = (float)v.y; o.z = (float)v.z; o.w = (float)v.w;
            *(float4*)(eout + (size_t)i * 4) = o;
        }
        return;
    }

    LSTM2G_PROLOGUE
    LSTM2G_CORE_LOOP

    // ---- epilogue: hb* = final H B-frags for both streams ----
    {
        const u16* wr  = llw + (size_t)(w * 16 + col) * 64 + quad * 8;
        short8 ll0 = *(const short8*)wr, ll1 = *(const short8*)(wr + 32);
        const u16* wr2 = lrw + (size_t)(w * 16 + col) * 64 + quad * 8;
        short8 lr0 = *(const short8*)wr2, lr1 = *(const short8*)(wr2 + 32);
        f32x4 bY = bias4(llb + w * 16 + quad * 4);

        const u16* xrA = X + (size_t)nodeA * 64 + quad * 8;
        short8 rxA0 = *(const short8*)xrA, rxA1 = *(const short8*)(xrA + 32);
        const u16* xrB = X + (size_t)nodeB * 64 + quad * 8;
        short8 rxB0 = *(const short8*)xrB, rxB1 = *(const short8*)(xrB + 32);

        f32x4 aA = MFMA16(ll0, hbA0, bY, 0, 0, 0);
        aA = MFMA16(ll1, hbA1, aA, 0, 0, 0);
        aA = MFMA16(lr0, rxA0, aA, 0, 0, 0);
        aA = MFMA16(lr1, rxA1, aA, 0, 0, 0);
        f32x4 aB = MFMA16(ll0, hbB0, bY, 0, 0, 0);
        aB = MFMA16(ll1, hbB1, aB, 0, 0, 0);
        aB = MFMA16(lr0, rxB0, aB, 0, 0, 0);
        aB = MFMA16(lr1, rxB1, aB, 0, 0, 0);

        u32 yA0 = pack_relu(aA[0], aA[1]), yA1 = pack_relu(aA[2], aA[3]);
        u32 yB0 = pack_relu(aB[0], aB[1]), yB1 = pack_relu(aB[2], aB[3]);
        *(uint2*)(Y1 + (size_t)nodeA * 64 + w * 16 + quad * 4) = (uint2){yA0, yA1};
        if (actB) *(uint2*)(Y1 + (size_t)nodeB * 64 + w * 16 + quad * 4) = (uint2){yB0, yB1};
        xwrite(bufY, 64, col,      quad, w, yA0, yA1);
        xwrite(bufY, 64, col + 16, quad, w, yB0, yB1);
        __syncthreads();

        const u16* wp = pw + (size_t)(w * 16 + col) * 64 + quad * 8;
        short8 p0 = *(const short8*)wp, p1 = *(const short8*)(wp + 32);
        f32x4 bp = bias4(pb + w * 16 + quad * 4);

        short8 ybA0 = xread(bufY, 64, col,      quad, 0);
        short8 ybA1 = xread(bufY, 64, col,      quad, 1);
        short8 ybB0 = xread(bufY, 64, col + 16, quad, 0);
        short8 ybB1 = xread(bufY, 64, col + 16, quad, 1);

        f32x4 a2A = MFMA16(p0, ybA0, bp, 0, 0, 0);
        a2A = MFMA16(p1, ybA1, a2A, 0, 0, 0);
        f32x4 a2B = MFMA16(p0, ybB0, bp, 0, 0, 0);
        a2B = MFMA16(p1, ybB1, a2B, 0, 0, 0);

        *(uint2*)(XP2 + (size_t)nodeA * 64 + w * 16 + quad * 4) =
            (uint2){pack_relu(a2A[0], a2A[1]), pack_relu(a2A[2], a2A[3])};
        if (actB) *(uint2*)(XP2 + (size_t)nodeB * 64 + w * 16 + quad * 4) =
            (uint2){pack_relu(a2B[0], a2B[1]), pack_relu(a2B[2], a2B[3])};
    }
}

// ---------------------------------------------------------------------------
// lstm_post: layer-2 LSTM + fused Y2[128] -> T1[192] -> T2[64] -> out[64] f32
// ---------------------------------------------------------------------------
__global__ __launch_bounds__(256, 3) void lstm_post(
    const u16* __restrict__ xp, const int* __restrict__ src,
    const u16* __restrict__ wihs, const u16* __restrict__ whhs,
    const u16* __restrict__ bih, const u16* __restrict__ bhh,
    const u16* __restrict__ Y1,                                  // [N,64]
    const u16* __restrict__ llw2, const u16* __restrict__ llb2,
    const u16* __restrict__ lrw2,                                // [128,64],[128],[128,64]
    const u16* __restrict__ w1m, const u16* __restrict__ b1m,    // [192,128],[192]
    const u16* __restrict__ w2m, const u16* __restrict__ b2m,    // [64,192],[64]
    const u16* __restrict__ w3m, const u16* __restrict__ b3m,    // [64,64],[64]
    float* __restrict__ outp, int N)
{
    __shared__ u16 xs[8 * 2048];        // 32KB staged x
    __shared__ float lds_b[256];        // 1KB
    __shared__ u16 lds_h[2][32 * 64];   // 8KB
    u16* bufA = (u16*)lds_h;            // 8KB: Y2 exchange (32x128), then T2 @64
    u16* bufB = xs;                     // 12KB of xs: T1 exchange (32x192)

    LSTM2G_PROLOGUE
    LSTM2G_CORE_LOOP

    // ---- epilogue ----
    {
        barrier_lds();   // bufA aliases lds_h: ensure all waves' final hb reads done

        const u16* yrA = Y1 + (size_t)nodeA * 64 + quad * 8;
        short8 ryA0 = *(const short8*)yrA, ryA1 = *(const short8*)(yrA + 32);
        const u16* yrB = Y1 + (size_t)nodeB * 64 + quad * 8;
        short8 ryB0 = *(const short8*)yrB, ryB1 = *(const short8*)(yrB + 32);

        // Y2 tiles jt = 2w, 2w+1
#pragma unroll
        for (int ti = 0; ti < 2; ++ti) {
            int jt = 2 * w + ti;
            const u16* wr = llw2 + (size_t)(jt * 16 + col) * 64 + quad * 8;
            short8 l0 = *(const short8*)wr, l1 = *(const short8*)(wr + 32);
            const u16* wr2 = lrw2 + (size_t)(jt * 16 + col) * 64 + quad * 8;
            short8 r0 = *(const short8*)wr2, r1 = *(const short8*)(wr2 + 32);
            f32x4 b0 = bias4(llb2 + jt * 16 + quad * 4);
            f32x4 aA = MFMA16(l0, hbA0, b0, 0, 0, 0);
            aA = MFMA16(l1, hbA1, aA, 0, 0, 0);
            aA = MFMA16(r0, ryA0, aA, 0, 0, 0);
            aA = MFMA16(r1, ryA1, aA, 0, 0, 0);
            xwrite(bufA, 128, col, quad, jt, pack_relu(aA[0], aA[1]), pack_relu(aA[2], aA[3]));
            f32x4 aB = MFMA16(l0, hbB0, b0, 0, 0, 0);
            aB = MFMA16(l1, hbB1, aB, 0, 0, 0);
            aB = MFMA16(r0, ryB0, aB, 0, 0, 0);
            aB = MFMA16(r1, ryB1, aB, 0, 0, 0);
            xwrite(bufA, 128, col + 16, quad, jt, pack_relu(aB[0], aB[1]), pack_relu(aB[2], aB[3]));
        }
        __syncthreads();

        short8 y2A[4], y2B[4];
#pragma unroll
        for (int kc = 0; kc < 4; ++kc) {
            y2A[kc] = xread(bufA, 128, col,      quad, kc);
            y2B[kc] = xread(bufA, 128, col + 16, quad, kc);
        }
        // T1 tiles jt = 3w..3w+2, K=128
#pragma unroll
        for (int ti = 0; ti < 3; ++ti) {
            int jt = 3 * w + ti;
            const u16* wr = w1m + (size_t)(jt * 16 + col) * 128 + quad * 8;
            short8 wk[4];
#pragma unroll
            for (int kc = 0; kc < 4; ++kc) wk[kc] = *(const short8*)(wr + kc * 32);
            f32x4 b1v = bias4(b1m + jt * 16 + quad * 4);
            f32x4 aA = b1v, aB = b1v;
#pragma unroll
            for (int kc = 0; kc < 4; ++kc) {
                aA = MFMA16(wk[kc], y2A[kc], aA, 0, 0, 0);
                aB = MFMA16(wk[kc], y2B[kc], aB, 0, 0, 0);
            }
            xwrite(bufB, 192, col,      quad, jt, pack_relu(aA[0], aA[1]), pack_relu(aA[2], aA[3]));
            xwrite(bufB, 192, col + 16, quad, jt, pack_relu(aB[0], aB[1]), pack_relu(aB[2], aB[3]));
        }
        __syncthreads();

        short8 t1A[6], t1B[6];
#pragma unroll
        for (int kc = 0; kc < 6; ++kc) {
            t1A[kc] = xread(bufB, 192, col,      quad, kc);
            t1B[kc] = xread(bufB, 192, col + 16, quad, kc);
        }
        // T2 tile jt=w, K=192 (bufA reuse @ stride 64 — Y2 reads completed pre-barrier)
        {
            const u16* wr = w2m + (size_t)(w * 16 + col) * 192 + quad * 8;
            f32x4 b2v = bias4(b2m + w * 16 + quad * 4);
            f32x4 aA = b2v, aB = b2v;
#pragma unroll
            for (int kc = 0; kc < 6; ++kc) {
                short8 wk = *(const short8*)(wr + kc * 32);
                aA = MFMA16(wk, t1A[kc], aA, 0, 0, 0);
                aB = MFMA16(wk, t1B[kc], aB, 0, 0, 0);
            }
            xwrite(bufA, 64, col,      quad, w, pack_relu(aA[0], aA[1]), pack_relu(aA[2], aA[3]));
            xwrite(bufA, 64, col + 16, quad, w, pack_relu(aB[0], aB[1]), pack_relu(aB[2], aB[3]));
        }
        __syncthreads();

        short8 t2A0 = xread(bufA, 64, col,      quad, 0);
        short8 t2A1 = xread(bufA, 64, col,      quad, 1);
        short8 t2B0 = xread(bufA, 64, col + 16, quad, 0);
        short8 t2B1 = xread(bufA, 64, col + 16, quad, 1);
        // out tile jt=w, K=64, f32 store
        {
            const u16* wr = w3m + (size_t)(w * 16 + col) * 64 + quad * 8;
            short8 l0 = *(const short8*)wr, l1 = *(const short8*)(wr + 32);
            f32x4 b3v = bias4(b3m + w * 16 + quad * 4);
            f32x4 aA = MFMA16(l0, t2A0, b3v, 0, 0, 0);
            aA = MFMA16(l1, t2A1, aA, 0, 0, 0);
            f32x4 aB = MFMA16(l0, t2B0, b3v, 0, 0, 0);
            aB = MFMA16(l1, t2B1, aB, 0, 0, 0);
            float4 oA;
            oA.x = fmaxf(aA[0], 0.f); oA.y = fmaxf(aA[1], 0.f);
            oA.z = fmaxf(aA[2], 0.f); oA.w = fmaxf(aA[3], 0.f);
            *(float4*)(outp + (size_t)nodeA * 64 + w * 16 + quad * 4) = oA;
            if (actB) {
                float4 oB;
                oB.x = fmaxf(aB[0], 0.f); oB.y = fmaxf(aB[1], 0.f);
                oB.z = fmaxf(aB[2], 0.f); oB.w = fmaxf(aB[3], 0.f);
                *(float4*)(outp + (size_t)nodeB * 64 + w * 16 + quad * 4) = oB;
            }
        }
    }
}

// ---------------------------------------------------------------------------
extern "C" void kernel_launch(void* const* d_in, const int* in_sizes, int n_in,
                              void* d_out, int out_size, void* d_ws, size_t ws_size,
                              hipStream_t stream)
{
    const u16* x       = (const u16*)d_in[0];
    const int* edge    = (const int*)d_in[1];
    const u16* p1_pw   = (const u16*)d_in[3];
    const u16* p1_pb   = (const u16*)d_in[4];
    const u16* p1_wih  = (const u16*)d_in[5];
    const u16* p1_whh  = (const u16*)d_in[6];
    const u16* p1_bih  = (const u16*)d_in[7];
    const u16* p1_bhh  = (const u16*)d_in[8];
    const u16* p1_llw  = (const u16*)d_in[9];
    const u16* p1_llb  = (const u16*)d_in[10];
    const u16* p1_lrw  = (const u16*)d_in[11];
    const u16* p2_pw   = (const u16*)d_in[12];
    const u16* p2_pb   = (const u16*)d_in[13];
    const u16* p2_wih  = (const u16*)d_in[14];
    const u16* p2_whh  = (const u16*)d_in[15];
    const u16* p2_bih  = (const u16*)d_in[16];
    const u16* p2_bhh  = (const u16*)d_in[17];
    const u16* p2_llw  = (const u16*)d_in[18];
    const u16* p2_llb  = (const u16*)d_in[19];
    const u16* p2_lrw  = (const u16*)d_in[20];
    const u16* lin1w   = (const u16*)d_in[21];
    const u16* lin1b   = (const u16*)d_in[22];
    const u16* lin2w   = (const u16*)d_in[23];
    const u16* lin2b   = (const u16*)d_in[24];
    const u16* lin3w   = (const u16*)d_in[25];
    const u16* lin3b   = (const u16*)d_in[26];
    (void)n_in; (void)ws_size;

    const int N  = in_sizes[0] / 64;     // 50000
    const int E2 = in_sizes[1];          // edge_index element count
    const int* srcIdx = edge;

    // workspace: scaled weights 128KB @0; xp1 @1MB; xp2 @8MB; Y1 @15MB
    char* w = (char*)d_ws;
    u16* wss   = (u16*)(w);
    u16* xp1   = (u16*)(w + 1u  * 1024 * 1024);
    u16* xp2   = (u16*)(w + 8u  * 1024 * 1024);
    u16* bufY1 = (u16*)(w + 15u * 1024 * 1024);
    u16* wih1s = wss;
    u16* whh1s = wss + 16384;
    u16* wih2s = wss + 32768;
    u16* whh2s = wss + 49152;

    float* out_h    = (float*)d_out;
    float* out_edge = (float*)d_out + (size_t)N * 64;
    (void)out_size;

    const int gb  = (N + 63) / 64;       // 782 (xp1 GEMM blocks)
    const int gbl = (N + 31) / 32;       // 1563 (lstm blocks, 32 nodes each)
    const int n4 = E2 / 4;
    const int eb = (n4 + 255) / 256;     // edge-cast blocks (now in lstm_mid)

    dim3 block(256);

    hipLaunchKernelGGL(k_pre, dim3(gb + 64), block, 0, stream,
                       x, p1_pw, p1_pb, xp1, N, gb,
                       p1_wih, p1_whh, p2_wih, p2_whh, wss);
    hipLaunchKernelGGL(lstm_mid, dim3(gbl + eb), block, 0, stream,
                       xp1, srcIdx, wih1s, whh1s, p1_bih, p1_bhh,
                       x, p1_llw, p1_llb, p1_lrw, p2_pw, p2_pb, bufY1, xp2, N,
                       out_edge, n4, gbl);
    hipLaunchKernelGGL(lstm_post, dim3(gbl), block, 0, stream,
                       xp2, srcIdx, wih2s, whh2s, p2_bih, p2_bhh,
                       bufY1, p2_llw, p2_llb, p2_lrw,
                       lin1w, lin1b, lin2w, lin2b, lin3w, lin3b, out_h, N);
}

// Round 11
// 285.217 us; speedup vs baseline: 2.3865x; 1.0094x over previous
//
#include <hip/hip_runtime.h>
#include <hip/hip_bf16.h>

typedef unsigned short u16;
typedef unsigned int u32;
typedef __attribute__((ext_vector_type(8))) short short8;    // 8 bf16 MFMA A/B frag
typedef __attribute__((ext_vector_type(4))) float f32x4;

#define KS1 1.44269504f   // log2(e)
#define KS2 2.88539008f   // 2*log2(e)

__device__ __forceinline__ float bf2f(u16 u) {
    union { u32 i; float f; } v; v.i = ((u32)u) << 16; return v.f;
}
__device__ __forceinline__ u16 f2bf(float f) {            // RNE
    union { float f; u32 i; } v; v.f = f;
    u32 r = v.i + 0x7fffu + ((v.i >> 16) & 1u);
    return (u16)(r >> 16);
}
// pack two f32 -> two bf16 (truncation) in ONE v_perm (h state only)
__device__ __forceinline__ u32 pack_bf2(float lo, float hi) {
    return __builtin_amdgcn_perm(__float_as_uint(hi), __float_as_uint(lo), 0x07060302u);
}
// relu + RNE pack (epilogue intermediates)
__device__ __forceinline__ u32 pack_relu(float a, float b) {
    return (u32)f2bf(fmaxf(a, 0.f)) | ((u32)f2bf(fmaxf(b, 0.f)) << 16);
}
__device__ __forceinline__ f32x4 bias4(const u16* b) {
    uint2 u = *(const uint2*)b;
    f32x4 r;
    r[0] = bf2f((u16)(u.x & 0xffffu)); r[1] = bf2f((u16)(u.x >> 16));
    r[2] = bf2f((u16)(u.y & 0xffffu)); r[3] = bf2f((u16)(u.y >> 16));
    return r;
}
// LDS-only barrier: lgkmcnt(0)+s_barrier. Does NOT drain vmcnt, so the
// global_load_lds refills stay in flight across step barriers.
__device__ __forceinline__ void barrier_lds() {
    asm volatile("s_waitcnt lgkmcnt(0)" ::: "memory");
    __builtin_amdgcn_s_barrier();
}
// direct global->LDS 16B copy: lane writes at ldsbase + lane*16 (HW rule),
// so the XOR-swizzle is applied on the per-lane GLOBAL source instead.
__device__ __forceinline__ void gload_lds16(const u16* g, u16* l) {
    __builtin_amdgcn_global_load_lds(
        (const __attribute__((address_space(1))) u32*)(const void*)g,
        (__attribute__((address_space(3))) u32*)(void*)l, 16, 0, 0);
}
// XOR-swizzled exchange buffer (proven bank-free: <=2-way per 16-lane quarter).
__device__ __forceinline__ void xwrite(u16* buf, int D2, int row, int quad, int jt, u32 w0, u32 w1) {
    int ch = jt * 2 + (quad >> 1);
    *(uint2*)(buf + row * D2 + ((ch ^ (row & 7)) << 3) + ((quad & 1) << 2)) = (uint2){w0, w1};
}
__device__ __forceinline__ short8 xread(const u16* buf, int D2, int row, int quad, int kc) {
    return *(const short8*)(buf + row * D2 + (((kc * 4 + quad) ^ (row & 7)) << 3));
}
#define MFMA16 __builtin_amdgcn_mfma_f32_16x16x32_bf16

// ---------------------------------------------------------------------------
// k_pre: [0,gb) xp1 GEMM; [gb,gb+64) scaled weight copy.
// (edge cast lives in lstm_mid's grid tail -- hides under the latency-bound
// LSTM instead of serializing here; r10-verified, ~10us saved)
// ---------------------------------------------------------------------------
__global__ __launch_bounds__(256) void k_pre(
    const u16* __restrict__ X, const u16* __restrict__ pw, const u16* __restrict__ pb,
    u16* __restrict__ XP, int M, int gb,
    const u16* __restrict__ w1i, const u16* __restrict__ w1h,
    const u16* __restrict__ w2i, const u16* __restrict__ w2h,
    u16* __restrict__ wss)
{
    const int bid = blockIdx.x;
    const int tid = threadIdx.x;
    if (bid >= gb) {
        int wb = bid - gb;                 // 0..63
        int mi = wb >> 4;
        const u16* Wsrc = (mi == 0) ? w1i : (mi == 1) ? w1h : (mi == 2) ? w2i : w2h;
        u16* Wdst = wss + (size_t)mi * 16384;
        int e0 = (wb & 15) * 1024 + tid * 4;
        int row = e0 >> 6;
        float sc = (row >= 128 && row < 192) ? KS2 : KS1;
        uint2 v = *(const uint2*)(Wsrc + e0);
        u32 a = (u32)f2bf(bf2f((u16)(v.x & 0xffffu)) * sc)
              | ((u32)f2bf(bf2f((u16)(v.x >> 16)) * sc) << 16);
        u32 b = (u32)f2bf(bf2f((u16)(v.y & 0xffffu)) * sc)
              | ((u32)f2bf(bf2f((u16)(v.y >> 16)) * sc) << 16);
        *(uint2*)(Wdst + e0) = (uint2){a, b};
        return;
    }
    const int lane = tid & 63;
    const int wave = tid >> 6;
    const int row0 = (bid * 4 + wave) * 16;
    if (row0 >= M) return;
    const int col  = lane & 15;
    const int quad = lane >> 4;

    f32x4 c1[4];
#pragma unroll
    for (int jt = 0; jt < 4; ++jt) c1[jt] = (f32x4){0.f, 0.f, 0.f, 0.f};
    {
        const u16* xrow = X  + (size_t)(row0 + col) * 64 + quad * 8;
        const u16* wrow = pw + (size_t)col * 64 + quad * 8;
#pragma unroll
        for (int kc = 0; kc < 64; kc += 32) {
            short8 a = *(const short8*)(xrow + kc);
#pragma unroll
            for (int jt = 0; jt < 4; ++jt) {
                short8 b = *(const short8*)(wrow + (size_t)jt * 16 * 64 + kc);
                c1[jt] = MFMA16(a, b, c1[jt], 0, 0, 0);
            }
        }
    }
#pragma unroll
    for (int jt = 0; jt < 4; ++jt) {
        float bias = bf2f(pb[jt * 16 + col]);
#pragma unroll
        for (int r = 0; r < 4; ++r) {
            float v = fmaxf(c1[jt][r] + bias, 0.f);
            XP[(size_t)(row0 + quad * 4 + r) * 64 + jt * 16 + col] = f2bf(v);
        }
    }
}

// ===========================================================================
// LSTM v19 = r8's verified v16 VERBATIM (drainless 2-stream, 93.3us/kernel,
// spill-free: VGPR 84, WRITE 12.5MB) -- bc stays as a per-step LDS broadcast
// read (r10 proved hoisting it to VGPRs crosses the register cliff and
// scratch-spills: WRITE 31MB, +7us). Only delta vs r8: edge cast folded into
// lstm_mid's grid tail (r10-verified clean).
// Session ledger: the ~93us/kernel wall is invariant across 1/2/3-stream ILP,
// 25-61% occupancy, barrier-free, and phased staging -- it is a trans-issue +
// barrier-chain floor at the register-capped TLP of this structure.
// ===========================================================================

#define NONLIN(ACC, CST, HW0, HW1)                                             \
    {                                                                          \
        float hv[4];                                                           \
        _Pragma("unroll") for (int r = 0; r < 4; ++r) {                        \
            float iv = ACC[0][r], fv = ACC[1][r], gv = ACC[2][r], ov = ACC[3][r]; \
            float e_i = __builtin_amdgcn_exp2f(-iv);                           \
            float e_f = __builtin_amdgcn_exp2f(-fv);                           \
            float e_g = __builtin_amdgcn_exp2f(gv);                            \
            float af  = 1.0f + e_f;                                            \
            float P   = (1.0f + e_i) * (1.0f + e_g);                           \
            float tt  = __builtin_fmaf(e_g, KS2, -KS2);                        \
            float num = __builtin_fmaf(tt, af, CST[r] * P);                    \
            float cn  = num * __builtin_amdgcn_rcpf(af * P);                   \
            CST[r] = cn;                                                       \
            float e_c = __builtin_amdgcn_exp2f(cn);                            \
            float e_o = __builtin_amdgcn_exp2f(-ov);                           \
            float roc = __builtin_amdgcn_rcpf((1.0f + e_o) * (1.0f + e_c));    \
            hv[r] = (e_c - 1.0f) * roc;                                        \
        }                                                                      \
        HW0 = pack_bf2(hv[0], hv[1]);                                          \
        HW1 = pack_bf2(hv[2], hv[3]);                                          \
    }

#define LSTM2G_PROLOGUE                                                        \
    const int tid  = threadIdx.x;                                              \
    const int lane = tid & 63;                                                 \
    const int w    = tid >> 6;                                                 \
    const int col  = lane & 15;                                                \
    const int quad = lane >> 4;                                                \
    const int node0 = blockIdx.x * 32;                                         \
    if (node0 >= N) return;                                                    \
    const bool actB = (node0 + 32 <= N);                                       \
    const int nodeA = node0 + col;                                             \
    const int nodeB = actB ? (node0 + 16 + col) : nodeA;                       \
    {                                                                          \
        int j = tid;                                                           \
        float sc = (j >= 128 && j < 192) ? KS2 : KS1;                          \
        lds_b[j] = (bf2f(bih[j]) + bf2f(bhh[j])) * sc;                         \
    }                                                                          \
    const int rlo = lane >> 3;                 /* row-within-8 */              \
    const u16* gch = xp + (((lane & 7) ^ rlo) << 3);  /* pre-swizzled chunk */ \
    int i2k[4], i3k[4];                                                        \
    _Pragma("unroll") for (int k = 0; k < 4; ++k) {                            \
        int rn = node0 + k * 8 + rlo; if (rn >= N) rn = N - 1;                 \
        const int* sp = src + (size_t)rn * 16;                                 \
        int i0 = sp[w], i1 = sp[4 + w];                                        \
        i2k[k] = sp[8 + w]; i3k[k] = sp[12 + w];                               \
        gload_lds16(gch + (size_t)i0 * 64, xs + w * 2048 + k * 512);           \
        gload_lds16(gch + (size_t)i1 * 64, xs + (4 + w) * 2048 + k * 512);     \
    }                                                                          \
    short8 wf[8], hf[8];                                                       \
    _Pragma("unroll") for (int g = 0; g < 4; ++g) {                            \
        int jt = w + 4 * g;                                                    \
        const u16* wi = wihs + (size_t)(jt * 16 + col) * 64 + quad * 8;        \
        const u16* wh = whhs + (size_t)(jt * 16 + col) * 64 + quad * 8;        \
        wf[g * 2 + 0] = *(const short8*)(wi);                                  \
        wf[g * 2 + 1] = *(const short8*)(wi + 32);                             \
        hf[g * 2 + 0] = *(const short8*)(wh);                                  \
        hf[g * 2 + 1] = *(const short8*)(wh + 32);                             \
    }                                                                          \
    __syncthreads();                                                           \
    const int q0 = quad ^ (col & 7);

#define LSTM2G_CORE_LOOP                                                       \
    short8 z8 = (short8){0,0,0,0,0,0,0,0};                                     \
    short8 hbA0 = z8, hbA1 = z8, hbB0 = z8, hbB1 = z8;                         \
    float cA[4], cB[4];                                                        \
    _Pragma("unroll") for (int i = 0; i < 4; ++i) { cA[i] = 0.f; cB[i] = 0.f; }\
    _Pragma("unroll 1") for (int t = 0; t < 16; ++t) {                         \
        if (t == 7 || t == 11)                                                 \
            asm volatile("s_waitcnt vmcnt(0)" ::: "memory");                   \
        const u16* pS = xs + ((((t >> 2) & 1) * 4 + (t & 3)) * 2048);          \
        const u16* pA = pS + col * 64;                                         \
        short8 xbA0 = *(const short8*)(pA + q0 * 8);                           \
        short8 xbA1 = *(const short8*)(pA + ((q0 ^ 4) << 3));                  \
        const u16* pB = pS + (col + 16) * 64;                                  \
        short8 xbB0 = *(const short8*)(pB + q0 * 8);                           \
        short8 xbB1 = *(const short8*)(pB + ((q0 ^ 4) << 3));                  \
        if (t == 4) {   /* refill steps 8..11 into buffer0 (slot w) */         \
            _Pragma("unroll") for (int k = 0; k < 4; ++k)                      \
                gload_lds16(gch + (size_t)i2k[k] * 64, xs + w * 2048 + k * 512); \
        }                                                                      \
        if (t == 8) {   /* refill steps 12..15 into buffer1 (slot 4+w) */      \
            _Pragma("unroll") for (int k = 0; k < 4; ++k)                      \
                gload_lds16(gch + (size_t)i3k[k] * 64, xs + (4 + w) * 2048 + k * 512); \
        }                                                                      \
        f32x4 accA[4], accB[4];                                                \
        _Pragma("unroll") for (int g = 0; g < 4; ++g) {                        \
            f32x4 bc = *(const f32x4*)(lds_b + (w + 4 * g) * 16 + quad * 4);   \
            accA[g] = MFMA16(wf[g * 2 + 0], xbA0, bc, 0, 0, 0);                \
            accB[g] = MFMA16(wf[g * 2 + 0], xbB0, bc, 0, 0, 0);                \
            accA[g] = MFMA16(wf[g * 2 + 1], xbA1, accA[g], 0, 0, 0);           \
            accB[g] = MFMA16(wf[g * 2 + 1], xbB1, accB[g], 0, 0, 0);           \
        }                                                                      \
        if (t > 0) {                                                           \
            _Pragma("unroll") for (int g = 0; g < 4; ++g) {                    \
                accA[g] = MFMA16(hf[g * 2 + 0], hbA0, accA[g], 0, 0, 0);       \
                accB[g] = MFMA16(hf[g * 2 + 0], hbB0, accB[g], 0, 0, 0);       \
                accA[g] = MFMA16(hf[g * 2 + 1], hbA1, accA[g], 0, 0, 0);       \
                accB[g] = MFMA16(hf[g * 2 + 1], hbB1, accB[g], 0, 0, 0);       \
            }                                                                  \
        }                                                                      \
        u32 hwA0, hwA1, hwB0, hwB1;                                            \
        NONLIN(accA, cA, hwA0, hwA1)                                           \
        NONLIN(accB, cB, hwB0, hwB1)                                           \
        u16* hbuf = lds_h[t & 1];                                              \
        xwrite(hbuf, 64, col,      quad, w, hwA0, hwA1);                       \
        xwrite(hbuf, 64, col + 16, quad, w, hwB0, hwB1);                       \
        barrier_lds();                                                         \
        hbA0 = xread(hbuf, 64, col,      quad, 0);                             \
        hbA1 = xread(hbuf, 64, col,      quad, 1);                             \
        hbB0 = xread(hbuf, 64, col + 16, quad, 0);                             \
        hbB1 = xread(hbuf, 64, col + 16, quad, 1);                             \
    }

// ---------------------------------------------------------------------------
// lstm_mid: layer-1 LSTM + fused Y1 + xp2; tail blocks do the edge cast
// ---------------------------------------------------------------------------
__global__ __launch_bounds__(256, 3) void lstm_mid(
    const u16* __restrict__ xp, const int* __restrict__ src,
    const u16* __restrict__ wihs, const u16* __restrict__ whhs,
    const u16* __restrict__ bih, const u16* __restrict__ bhh,
    const u16* __restrict__ X,                                   // root x [N,64]
    const u16* __restrict__ llw, const u16* __restrict__ llb,
    const u16* __restrict__ lrw,
    const u16* __restrict__ pw, const u16* __restrict__ pb,
    u16* __restrict__ Y1, u16* __restrict__ XP2, int N,
    float* __restrict__ eout, int n4, int nlstm)
{
    __shared__ u16 xs[8 * 2048];        // 32KB staged x (2 phases x 4 steps x 32 nodes)
    __shared__ float lds_b[256];        // 1KB scaled bias'
    __shared__ u16 lds_h[2][32 * 64];   // 8KB h double buffer
    u16* bufY = xs;                     // epilogue alias (xs dead after loop)

    if ((int)blockIdx.x >= nlstm) {     // edge-cast tail blocks (pure BW)
        int i = ((int)blockIdx.x - nlstm) * 256 + (int)threadIdx.x;
        if (i < n4) {
            int4 v = *(const int4*)(src + (size_t)i * 4);
            float4 o;
            o.x = (float)v.x; o.y = (float)v.y; o.z = (float)v.z; o.w = (float)v.w;
            *(float4*)(eout + (size_t)i * 4) = o;
        }
        return;
    }

    LSTM2G_PROLOGUE
    LSTM2G_CORE_LOOP

    // ---- epilogue: hb* = final H B-frags for both streams ----
    {
        const u16* wr  = llw + (size_t)(w * 16 + col) * 64 + quad * 8;
        short8 ll0 = *(const short8*)wr, ll1 = *(const short8*)(wr + 32);
        const u16* wr2 = lrw + (size_t)(w * 16 + col) * 64 + quad * 8;
        short8 lr0 = *(const short8*)wr2, lr1 = *(const short8*)(wr2 + 32);
        f32x4 bY = bias4(llb + w * 16 + quad * 4);

        const u16* xrA = X + (size_t)nodeA * 64 + quad * 8;
        short8 rxA0 = *(const short8*)xrA, rxA1 = *(const short8*)(xrA + 32);
        const u16* xrB = X + (size_t)nodeB * 64 + quad * 8;
        short8 rxB0 = *(const short8*)xrB, rxB1 = *(const short8*)(xrB + 32);

        f32x4 aA = MFMA16(ll0, hbA0, bY, 0, 0, 0);
        aA = MFMA16(ll1, hbA1, aA, 0, 0, 0);
        aA = MFMA16(lr0, rxA0, aA, 0, 0, 0);
        aA = MFMA16(lr1, rxA1, aA, 0, 0, 0);
        f32x4 aB = MFMA16(ll0, hbB0, bY, 0, 0, 0);
        aB = MFMA16(ll1, hbB1, aB, 0, 0, 0);
        aB = MFMA16(lr0, rxB0, aB, 0, 0, 0);
        aB = MFMA16(lr1, rxB1, aB, 0, 0, 0);

        u32 yA0 = pack_relu(aA[0], aA[1]), yA1 = pack_relu(aA[2], aA[3]);
        u32 yB0 = pack_relu(aB[0], aB[1]), yB1 = pack_relu(aB[2], aB[3]);
        *(uint2*)(Y1 + (size_t)nodeA * 64 + w * 16 + quad * 4) = (uint2){yA0, yA1};
        if (actB) *(uint2*)(Y1 + (size_t)nodeB * 64 + w * 16 + quad * 4) = (uint2){yB0, yB1};
        xwrite(bufY, 64, col,      quad, w, yA0, yA1);
        xwrite(bufY, 64, col + 16, quad, w, yB0, yB1);
        __syncthreads();

        const u16* wp = pw + (size_t)(w * 16 + col) * 64 + quad * 8;
        short8 p0 = *(const short8*)wp, p1 = *(const short8*)(wp + 32);
        f32x4 bp = bias4(pb + w * 16 + quad * 4);

        short8 ybA0 = xread(bufY, 64, col,      quad, 0);
        short8 ybA1 = xread(bufY, 64, col,      quad, 1);
        short8 ybB0 = xread(bufY, 64, col + 16, quad, 0);
        short8 ybB1 = xread(bufY, 64, col + 16, quad, 1);

        f32x4 a2A = MFMA16(p0, ybA0, bp, 0, 0, 0);
        a2A = MFMA16(p1, ybA1, a2A, 0, 0, 0);
        f32x4 a2B = MFMA16(p0, ybB0, bp, 0, 0, 0);
        a2B = MFMA16(p1, ybB1, a2B, 0, 0, 0);

        *(uint2*)(XP2 + (size_t)nodeA * 64 + w * 16 + quad * 4) =
            (uint2){pack_relu(a2A[0], a2A[1]), pack_relu(a2A[2], a2A[3])};
        if (actB) *(uint2*)(XP2 + (size_t)nodeB * 64 + w * 16 + quad * 4) =
            (uint2){pack_relu(a2B[0], a2B[1]), pack_relu(a2B[2], a2B[3])};
    }
}

// ---------------------------------------------------------------------------
// lstm_post: layer-2 LSTM + fused Y2[128] -> T1[192] -> T2[64] -> out[64] f32
// ---------------------------------------------------------------------------
__global__ __launch_bounds__(256, 3) void lstm_post(
    const u16* __restrict__ xp, const int* __restrict__ src,
    const u16* __restrict__ wihs, const u16* __restrict__ whhs,
    const u16* __restrict__ bih, const u16* __restrict__ bhh,
    const u16* __restrict__ Y1,                                  // [N,64]
    const u16* __restrict__ llw2, const u16* __restrict__ llb2,
    const u16* __restrict__ lrw2,                                // [128,64],[128],[128,64]
    const u16* __restrict__ w1m, const u16* __restrict__ b1m,    // [192,128],[192]
    const u16* __restrict__ w2m, const u16* __restrict__ b2m,    // [64,192],[64]
    const u16* __restrict__ w3m, const u16* __restrict__ b3m,    // [64,64],[64]
    float* __restrict__ outp, int N)
{
    __shared__ u16 xs[8 * 2048];        // 32KB staged x
    __shared__ float lds_b[256];        // 1KB
    __shared__ u16 lds_h[2][32 * 64];   // 8KB
    u16* bufA = (u16*)lds_h;            // 8KB: Y2 exchange (32x128), then T2 @64
    u16* bufB = xs;                     // 12KB of xs: T1 exchange (32x192)

    LSTM2G_PROLOGUE
    LSTM2G_CORE_LOOP

    // ---- epilogue ----
    {
        barrier_lds();   // bufA aliases lds_h: ensure all waves' final hb reads done

        const u16* yrA = Y1 + (size_t)nodeA * 64 + quad * 8;
        short8 ryA0 = *(const short8*)yrA, ryA1 = *(const short8*)(yrA + 32);
        const u16* yrB = Y1 + (size_t)nodeB * 64 + quad * 8;
        short8 ryB0 = *(const short8*)yrB, ryB1 = *(const short8*)(yrB + 32);

        // Y2 tiles jt = 2w, 2w+1
#pragma unroll
        for (int ti = 0; ti < 2; ++ti) {
            int jt = 2 * w + ti;
            const u16* wr = llw2 + (size_t)(jt * 16 + col) * 64 + quad * 8;
            short8 l0 = *(const short8*)wr, l1 = *(const short8*)(wr + 32);
            const u16* wr2 = lrw2 + (size_t)(jt * 16 + col) * 64 + quad * 8;
            short8 r0 = *(const short8*)wr2, r1 = *(const short8*)(wr2 + 32);
            f32x4 b0 = bias4(llb2 + jt * 16 + quad * 4);
            f32x4 aA = MFMA16(l0, hbA0, b0, 0, 0, 0);
            aA = MFMA16(l1, hbA1, aA, 0, 0, 0);
            aA = MFMA16(r0, ryA0, aA, 0, 0, 0);
            aA = MFMA16(r1, ryA1, aA, 0, 0, 0);
            xwrite(bufA, 128, col, quad, jt, pack_relu(aA[0], aA[1]), pack_relu(aA[2], aA[3]));
            f32x4 aB = MFMA16(l0, hbB0, b0, 0, 0, 0);
            aB = MFMA16(l1, hbB1, aB, 0, 0, 0);
            aB = MFMA16(r0, ryB0, aB, 0, 0, 0);
            aB = MFMA16(r1, ryB1, aB, 0, 0, 0);
            xwrite(bufA, 128, col + 16, quad, jt, pack_relu(aB[0], aB[1]), pack_relu(aB[2], aB[3]));
        }
        __syncthreads();

        short8 y2A[4], y2B[4];
#pragma unroll
        for (int kc = 0; kc < 4; ++kc) {
            y2A[kc] = xread(bufA, 128, col,      quad, kc);
            y2B[kc] = xread(bufA, 128, col + 16, quad, kc);
        }
        // T1 tiles jt = 3w..3w+2, K=128
#pragma unroll
        for (int ti = 0; ti < 3; ++ti) {
            int jt = 3 * w + ti;
            const u16* wr = w1m + (size_t)(jt * 16 + col) * 128 + quad * 8;
            short8 wk[4];
#pragma unroll
            for (int kc = 0; kc < 4; ++kc) wk[kc] = *(const short8*)(wr + kc * 32);
            f32x4 b1v = bias4(b1m + jt * 16 + quad * 4);
            f32x4 aA = b1v, aB = b1v;
#pragma unroll
            for (int kc = 0; kc < 4; ++kc) {
                aA = MFMA16(wk[kc], y2A[kc], aA, 0, 0, 0);
                aB = MFMA16(wk[kc], y2B[kc], aB, 0, 0, 0);
            }
            xwrite(bufB, 192, col,      quad, jt, pack_relu(aA[0], aA[1]), pack_relu(aA[2], aA[3]));
            xwrite(bufB, 192, col + 16, quad, jt, pack_relu(aB[0], aB[1]), pack_relu(aB[2], aB[3]));
        }
        __syncthreads();

        short8 t1A[6], t1B[6];
#pragma unroll
        for (int kc = 0; kc < 6; ++kc) {
            t1A[kc] = xread(bufB, 192, col,      quad, kc);
            t1B[kc] = xread(bufB, 192, col + 16, quad, kc);
        }
        // T2 tile jt=w, K=192 (bufA reuse @ stride 64 — Y2 reads completed pre-barrier)
        {
            const u16* wr = w2m + (size_t)(w * 16 + col) * 192 + quad * 8;
            f32x4 b2v = bias4(b2m + w * 16 + quad * 4);
            f32x4 aA = b2v, aB = b2v;
#pragma unroll
            for (int kc = 0; kc < 6; ++kc) {
                short8 wk = *(const short8*)(wr + kc * 32);
                aA = MFMA16(wk, t1A[kc], aA, 0, 0, 0);
                aB = MFMA16(wk, t1B[kc], aB, 0, 0, 0);
            }
            xwrite(bufA, 64, col,      quad, w, pack_relu(aA[0], aA[1]), pack_relu(aA[2], aA[3]));
            xwrite(bufA, 64, col + 16, quad, w, pack_relu(aB[0], aB[1]), pack_relu(aB[2], aB[3]));
        }
        __syncthreads();

        short8 t2A0 = xread(bufA, 64, col,      quad, 0);
        short8 t2A1 = xread(bufA, 64, col,      quad, 1);
        short8 t2B0 = xread(bufA, 64, col + 16, quad, 0);
        short8 t2B1 = xread(bufA, 64, col + 16, quad, 1);
        // out tile jt=w, K=64, f32 store
        {
            const u16* wr = w3m + (size_t)(w * 16 + col) * 64 + quad * 8;
            short8 l0 = *(const short8*)wr, l1 = *(const short8*)(wr + 32);
            f32x4 b3v = bias4(b3m + w * 16 + quad * 4);
            f32x4 aA = MFMA16(l0, t2A0, b3v, 0, 0, 0);
            aA = MFMA16(l1, t2A1, aA, 0, 0, 0);
            f32x4 aB = MFMA16(l0, t2B0, b3v, 0, 0, 0);
            aB = MFMA16(l1, t2B1, aB, 0, 0, 0);
            float4 oA;
            oA.x = fmaxf(aA[0], 0.f); oA.y = fmaxf(aA[1], 0.f);
            oA.z = fmaxf(aA[2], 0.f); oA.w = fmaxf(aA[3], 0.f);
            *(float4*)(outp + (size_t)nodeA * 64 + w * 16 + quad * 4) = oA;
            if (actB) {
                float4 oB;
                oB.x = fmaxf(aB[0], 0.f); oB.y = fmaxf(aB[1], 0.f);
                oB.z = fmaxf(aB[2], 0.f); oB.w = fmaxf(aB[3], 0.f);
                *(float4*)(outp + (size_t)nodeB * 64 + w * 16 + quad * 4) = oB;
            }
        }
    }
}

// ---------------------------------------------------------------------------
extern "C" void kernel_launch(void* const* d_in, const int* in_sizes, int n_in,
                              void* d_out, int out_size, void* d_ws, size_t ws_size,
                              hipStream_t stream)
{
    const u16* x       = (const u16*)d_in[0];
    const int* edge    = (const int*)d_in[1];
    const u16* p1_pw   = (const u16*)d_in[3];
    const u16* p1_pb   = (const u16*)d_in[4];
    const u16* p1_wih  = (const u16*)d_in[5];
    const u16* p1_whh  = (const u16*)d_in[6];
    const u16* p1_bih  = (const u16*)d_in[7];
    const u16* p1_bhh  = (const u16*)d_in[8];
    const u16* p1_llw  = (const u16*)d_in[9];
    const u16* p1_llb  = (const u16*)d_in[10];
    const u16* p1_lrw  = (const u16*)d_in[11];
    const u16* p2_pw   = (const u16*)d_in[12];
    const u16* p2_pb   = (const u16*)d_in[13];
    const u16* p2_wih  = (const u16*)d_in[14];
    const u16* p2_whh  = (const u16*)d_in[15];
    const u16* p2_bih  = (const u16*)d_in[16];
    const u16* p2_bhh  = (const u16*)d_in[17];
    const u16* p2_llw  = (const u16*)d_in[18];
    const u16* p2_llb  = (const u16*)d_in[19];
    const u16* p2_lrw  = (const u16*)d_in[20];
    const u16* lin1w   = (const u16*)d_in[21];
    const u16* lin1b   = (const u16*)d_in[22];
    const u16* lin2w   = (const u16*)d_in[23];
    const u16* lin2b   = (const u16*)d_in[24];
    const u16* lin3w   = (const u16*)d_in[25];
    const u16* lin3b   = (const u16*)d_in[26];
    (void)n_in; (void)ws_size;

    const int N  = in_sizes[0] / 64;     // 50000
    const int E2 = in_sizes[1];          // edge_index element count
    const int* srcIdx = edge;

    // workspace: scaled weights 128KB @0; xp1 @1MB; xp2 @8MB; Y1 @15MB
    char* w = (char*)d_ws;
    u16* wss   = (u16*)(w);
    u16* xp1   = (u16*)(w + 1u  * 1024 * 1024);
    u16* xp2   = (u16*)(w + 8u  * 1024 * 1024);
    u16* bufY1 = (u16*)(w + 15u * 1024 * 1024);
    u16* wih1s = wss;
    u16* whh1s = wss + 16384;
    u16* wih2s = wss + 32768;
    u16* whh2s = wss + 49152;

    float* out_h    = (float*)d_out;
    float* out_edge = (float*)d_out + (size_t)N * 64;
    (void)out_size;

    const int gb  = (N + 63) / 64;       // 782 (xp1 GEMM blocks)
    const int gbl = (N + 31) / 32;       // 1563 (lstm blocks, 32 nodes each)
    const int n4 = E2 / 4;
    const int eb = (n4 + 255) / 256;     // edge-cast blocks (in lstm_mid's tail)

    dim3 block(256);

    hipLaunchKernelGGL(k_pre, dim3(gb + 64), block, 0, stream,
                       x, p1_pw, p1_pb, xp1, N, gb,
                       p1_wih, p1_whh, p2_wih, p2_whh, wss);
    hipLaunchKernelGGL(lstm_mid, dim3(gbl + eb), block, 0, stream,
                       xp1, srcIdx, wih1s, whh1s, p1_bih, p1_bhh,
                       x, p1_llw, p1_llb, p1_lrw, p2_pw, p2_pb, bufY1, xp2, N,
                       out_edge, n4, gbl);
    hipLaunchKernelGGL(lstm_post, dim3(gbl), block, 0, stream,
                       xp2, srcIdx, wih2s, whh2s, p2_bih, p2_bhh,
                       bufY1, p2_llw, p2_llb, p2_lrw,
                       lin1w, lin1b, lin2w, lin2b, lin3w, lin3b, out_h, N);
}

// Round 12
// 274.201 us; speedup vs baseline: 2.4824x; 1.0402x over previous
//
#include <hip/hip_runtime.h>
#include <hip/hip_bf16.h>

typedef unsigned short u16;
typedef unsigned int u32;
typedef __attribute__((ext_vector_type(8))) short short8;    // 8 bf16 MFMA A/B frag
typedef __attribute__((ext_vector_type(4))) float f32x4;

#define KS1 1.44269504f   // log2(e)
#define KS2 2.88539008f   // 2*log2(e)

__device__ __forceinline__ float bf2f(u16 u) {
    union { u32 i; float f; } v; v.i = ((u32)u) << 16; return v.f;
}
__device__ __forceinline__ u16 f2bf(float f) {            // RNE
    union { float f; u32 i; } v; v.f = f;
    u32 r = v.i + 0x7fffu + ((v.i >> 16) & 1u);
    return (u16)(r >> 16);
}
// pack two f32 -> two bf16 (truncation) in ONE v_perm (h state only)
__device__ __forceinline__ u32 pack_bf2(float lo, float hi) {
    return __builtin_amdgcn_perm(__float_as_uint(hi), __float_as_uint(lo), 0x07060302u);
}
// relu + RNE pack (epilogue intermediates)
__device__ __forceinline__ u32 pack_relu(float a, float b) {
    return (u32)f2bf(fmaxf(a, 0.f)) | ((u32)f2bf(fmaxf(b, 0.f)) << 16);
}
__device__ __forceinline__ f32x4 bias4(const u16* b) {
    uint2 u = *(const uint2*)b;
    f32x4 r;
    r[0] = bf2f((u16)(u.x & 0xffffu)); r[1] = bf2f((u16)(u.x >> 16));
    r[2] = bf2f((u16)(u.y & 0xffffu)); r[3] = bf2f((u16)(u.y >> 16));
    return r;
}
// XOR-swizzled exchange buffer (proven bank-free: <=2-way per 16-lane quarter).
__device__ __forceinline__ void xwrite(u16* buf, int D2, int row, int quad, int jt, u32 w0, u32 w1) {
    int ch = jt * 2 + (quad >> 1);
    *(uint2*)(buf + row * D2 + ((ch ^ (row & 7)) << 3) + ((quad & 1) << 2)) = (uint2){w0, w1};
}
__device__ __forceinline__ short8 xread(const u16* buf, int D2, int row, int quad, int kc) {
    return *(const short8*)(buf + row * D2 + (((kc * 4 + quad) ^ (row & 7)) << 3));
}
#define MFMA16 __builtin_amdgcn_mfma_f32_16x16x32_bf16

// ---------------------------------------------------------------------------
// k_pre: [0,gb) xp1 GEMM; [gb,gb+eb) edge cast; [gb+eb,+64) scaled weight copy
// (r4's measured-best arrangement; weight copy modernized to 64 vectorized
// blocks -- verified clean in r6/r8/r11)
// ---------------------------------------------------------------------------
__global__ __launch_bounds__(256) void k_pre(
    const u16* __restrict__ X, const u16* __restrict__ pw, const u16* __restrict__ pb,
    u16* __restrict__ XP, int M, int gb,
    const int* __restrict__ e, float* __restrict__ eout, int n4, int eb,
    const u16* __restrict__ w1i, const u16* __restrict__ w1h,
    const u16* __restrict__ w2i, const u16* __restrict__ w2h,
    u16* __restrict__ wss)
{
    const int bid = blockIdx.x;
    const int tid = threadIdx.x;
    if (bid >= gb + eb) {
        int wb = bid - gb - eb;            // 0..63
        int mi = wb >> 4;
        const u16* Wsrc = (mi == 0) ? w1i : (mi == 1) ? w1h : (mi == 2) ? w2i : w2h;
        u16* Wdst = wss + (size_t)mi * 16384;
        int e0 = (wb & 15) * 1024 + tid * 4;
        int row = e0 >> 6;
        float sc = (row >= 128 && row < 192) ? KS2 : KS1;
        uint2 v = *(const uint2*)(Wsrc + e0);
        u32 a = (u32)f2bf(bf2f((u16)(v.x & 0xffffu)) * sc)
              | ((u32)f2bf(bf2f((u16)(v.x >> 16)) * sc) << 16);
        u32 b = (u32)f2bf(bf2f((u16)(v.y & 0xffffu)) * sc)
              | ((u32)f2bf(bf2f((u16)(v.y >> 16)) * sc) << 16);
        *(uint2*)(Wdst + e0) = (uint2){a, b};
        return;
    }
    if (bid >= gb) {
        int i = (bid - gb) * 256 + tid;
        if (i < n4) {
            int4 v = *(const int4*)(e + (size_t)i * 4);
            float4 o;
            o.x = (float)v.x; o.y = (float)v.y; o.z = (float)v.z; o.w = (float)v.w;
            *(float4*)(eout + (size_t)i * 4) = o;
        }
        return;
    }
    const int lane = tid & 63;
    const int wave = tid >> 6;
    const int row0 = (bid * 4 + wave) * 16;
    if (row0 >= M) return;
    const int col  = lane & 15;
    const int quad = lane >> 4;

    f32x4 c1[4];
#pragma unroll
    for (int jt = 0; jt < 4; ++jt) c1[jt] = (f32x4){0.f, 0.f, 0.f, 0.f};
    {
        const u16* xrow = X  + (size_t)(row0 + col) * 64 + quad * 8;
        const u16* wrow = pw + (size_t)col * 64 + quad * 8;
#pragma unroll
        for (int kc = 0; kc < 64; kc += 32) {
            short8 a = *(const short8*)(xrow + kc);
#pragma unroll
            for (int jt = 0; jt < 4; ++jt) {
                short8 b = *(const short8*)(wrow + (size_t)jt * 16 * 64 + kc);
                c1[jt] = MFMA16(a, b, c1[jt], 0, 0, 0);
            }
        }
    }
#pragma unroll
    for (int jt = 0; jt < 4; ++jt) {
        float bias = bf2f(pb[jt * 16 + col]);
#pragma unroll
        for (int r = 0; r < 4; ++r) {
            float v = fmaxf(c1[jt][r] + bias, 0.f);
            XP[(size_t)(row0 + quad * 4 + r) * 64 + jt * 16 + col] = f2bf(v);
        }
    }
}

// ===========================================================================
// LSTM v11 (r4 measured-best, 279.5us total / 93.9us per LSTM kernel).
// GATHER-FREE INNER LOOP: 16 nodes / 4-wave block. Prologue bulk-stages ALL
// 16 steps' neighbor rows (32KB) into LDS (~8 pipelined 16B loads/wave, one
// drain, one barrier); the 16-step recurrence runs entirely from LDS+regs --
// no vmcnt in the loop, the per-step barrier drains only LDS ops.
// Staging layout: chunk c of row r at slot c^(r&7) (<=2-way on both
// ds_write_b128 and ds_read_b128 per 16-lane quarter). Epilogue exchange
// buffers alias the dead staging buffer (LDS ~37KB -> 3 blocks/CU).
// Session floor: ~93us/kernel invariant across 1/2/3-stream ILP, 25-61%
// occupancy, barrier-free, phased staging -- recurrence latency floor at
// the register-capped TLP (weight set spills past ~4 waves/SIMD).
// ===========================================================================

#define NONLIN(ACC, CST, HW0, HW1)                                             \
    {                                                                          \
        float hv[4];                                                           \
        _Pragma("unroll") for (int r = 0; r < 4; ++r) {                        \
            float iv = ACC[0][r], fv = ACC[1][r], gv = ACC[2][r], ov = ACC[3][r]; \
            float e_i = __builtin_amdgcn_exp2f(-iv);                           \
            float e_f = __builtin_amdgcn_exp2f(-fv);                           \
            float e_g = __builtin_amdgcn_exp2f(gv);                            \
            float af  = 1.0f + e_f;                                            \
            float P   = (1.0f + e_i) * (1.0f + e_g);                           \
            float tt  = __builtin_fmaf(e_g, KS2, -KS2);                        \
            float num = __builtin_fmaf(tt, af, CST[r] * P);                    \
            float cn  = num * __builtin_amdgcn_rcpf(af * P);                   \
            CST[r] = cn;                                                       \
            float e_c = __builtin_amdgcn_exp2f(cn);                            \
            float e_o = __builtin_amdgcn_exp2f(-ov);                           \
            float roc = __builtin_amdgcn_rcpf((1.0f + e_o) * (1.0f + e_c));    \
            hv[r] = (e_c - 1.0f) * roc;                                        \
        }                                                                      \
        HW0 = pack_bf2(hv[0], hv[1]);                                          \
        HW1 = pack_bf2(hv[2], hv[3]);                                          \
    }

// Prologue: bias, bulk x-staging (wave w stages steps w*4..w*4+3), weights.
#define LSTMS_PROLOGUE                                                         \
    const int tid  = threadIdx.x;                                              \
    const int lane = tid & 63;                                                 \
    const int w    = tid >> 6;                                                 \
    const int col  = lane & 15;                                                \
    const int quad = lane >> 4;                                                \
    const int node0 = blockIdx.x * 16;                                         \
    if (node0 >= N) return;                                                    \
    const int nodeA = node0 + col;                                             \
    const bool act  = nodeA < N;                                               \
    const int ndA   = act ? nodeA : (N - 1);                                   \
    {                                                                          \
        int j = tid;                                                           \
        float sc = (j >= 128 && j < 192) ? KS2 : KS1;                          \
        lds_b[j] = (bf2f(bih[j]) + bf2f(bhh[j])) * sc;                         \
    }                                                                          \
    {                                                                          \
        const int rr   = lane >> 3;          /* row-within-half 0..7 */        \
        const int ch   = lane & 7;           /* 16B chunk of the row */        \
        const int slot = ch ^ rr;            /* XOR slot (r&7 == rr) */        \
        _Pragma("unroll") for (int half = 0; half < 2; ++half) {               \
            int sik[4];                                                        \
            _Pragma("unroll") for (int k = 0; k < 4; ++k) {                    \
                int kk = half * 4 + k;                                         \
                int t  = w * 4 + (kk >> 1);                                    \
                int r  = (kk & 1) * 8 + rr;                                    \
                int nrow = node0 + r; if (nrow >= N) nrow = N - 1;             \
                sik[k] = src[nrow * 16 + t];                                   \
            }                                                                  \
            short8 vk[4];                                                      \
            _Pragma("unroll") for (int k = 0; k < 4; ++k)                      \
                vk[k] = *(const short8*)(xp + (size_t)sik[k] * 64 + ch * 8);   \
            _Pragma("unroll") for (int k = 0; k < 4; ++k) {                    \
                int kk = half * 4 + k;                                         \
                int t  = w * 4 + (kk >> 1);                                    \
                int r  = (kk & 1) * 8 + rr;                                    \
                *(short8*)(xs + t * 1024 + r * 64 + slot * 8) = vk[k];         \
            }                                                                  \
        }                                                                      \
    }                                                                          \
    short8 wf[8], hf[8];                                                       \
    _Pragma("unroll") for (int g = 0; g < 4; ++g) {                            \
        int jt = w + 4 * g;                                                    \
        const u16* wi = wihs + (size_t)(jt * 16 + col) * 64 + quad * 8;        \
        const u16* wh = whhs + (size_t)(jt * 16 + col) * 64 + quad * 8;        \
        wf[g * 2 + 0] = *(const short8*)(wi);                                  \
        wf[g * 2 + 1] = *(const short8*)(wi + 32);                             \
        hf[g * 2 + 0] = *(const short8*)(wh);                                  \
        hf[g * 2 + 1] = *(const short8*)(wh + 32);                             \
    }                                                                          \
    __syncthreads();                                                           \
    const int q0 = quad ^ (col & 7);                                           \
    short8 xbA0, xbA1;                                                         \
    {                                                                          \
        const u16* p = xs + col * 64;                                          \
        xbA0 = *(const short8*)(p + q0 * 8);                                   \
        xbA1 = *(const short8*)(p + (q0 ^ 4) * 8);                             \
    }

#define LSTMS_CORE_LOOP                                                        \
    short8 hbA0 = (short8){0,0,0,0,0,0,0,0};                                   \
    short8 hbA1 = hbA0;                                                        \
    float cA[4];                                                               \
    _Pragma("unroll") for (int i = 0; i < 4; ++i) cA[i] = 0.f;                 \
    _Pragma("unroll 1") for (int t = 0; t < 16; ++t) {                         \
        u16* hbuf = lds_h[t & 1];                                              \
        f32x4 acc[4];                                                          \
        _Pragma("unroll") for (int g = 0; g < 4; ++g) {                        \
            f32x4 bc = *(const f32x4*)(lds_b + (w + 4 * g) * 16 + quad * 4);   \
            acc[g] = MFMA16(wf[g * 2 + 0], xbA0, bc, 0, 0, 0);                 \
            acc[g] = MFMA16(wf[g * 2 + 1], xbA1, acc[g], 0, 0, 0);             \
        }                                                                      \
        short8 xn0 = xbA0, xn1 = xbA1;                                         \
        if (t < 15) {                                                          \
            const u16* p = xs + (t + 1) * 1024 + col * 64;                     \
            xn0 = *(const short8*)(p + q0 * 8);                                \
            xn1 = *(const short8*)(p + (q0 ^ 4) * 8);                          \
        }                                                                      \
        if (t > 0) {                                                           \
            _Pragma("unroll") for (int g = 0; g < 4; ++g) {                    \
                acc[g] = MFMA16(hf[g * 2 + 0], hbA0, acc[g], 0, 0, 0);         \
                acc[g] = MFMA16(hf[g * 2 + 1], hbA1, acc[g], 0, 0, 0);         \
            }                                                                  \
        }                                                                      \
        u32 hwA0, hwA1;                                                        \
        NONLIN(acc, cA, hwA0, hwA1)                                            \
        xwrite(hbuf, 64, col, quad, w, hwA0, hwA1);                            \
        __syncthreads();                                                       \
        hbA0 = xread(hbuf, 64, col, quad, 0);                                  \
        hbA1 = xread(hbuf, 64, col, quad, 1);                                  \
        xbA0 = xn0; xbA1 = xn1;                                                \
    }

// ---------------------------------------------------------------------------
// lstm_mid: layer-1 LSTM + fused Y1 + xp2
// ---------------------------------------------------------------------------
__global__ __launch_bounds__(256, 4) void lstm_mid(
    const u16* __restrict__ xp, const int* __restrict__ src,
    const u16* __restrict__ wihs, const u16* __restrict__ whhs,
    const u16* __restrict__ bih, const u16* __restrict__ bhh,
    const u16* __restrict__ X,                                   // root x [N,64]
    const u16* __restrict__ llw, const u16* __restrict__ llb,
    const u16* __restrict__ lrw,
    const u16* __restrict__ pw, const u16* __restrict__ pb,
    u16* __restrict__ Y1, u16* __restrict__ XP2, int N)
{
    __shared__ u16 xs[16 * 1024];       // 32KB staged x (16 steps x 16 nodes x 64)
    __shared__ float lds_b[256];        // 1KB scaled bias'
    __shared__ u16 lds_h[2][16 * 64];   // 4KB h double buffer
    u16* bufY = xs;                     // epilogue alias (xs dead after loop)

    LSTMS_PROLOGUE
    LSTMS_CORE_LOOP

    // ---- epilogue: hbA0/hbA1 = final H B-frags ----
    {
        const u16* wr  = llw + (size_t)(w * 16 + col) * 64 + quad * 8;
        short8 ll0 = *(const short8*)wr, ll1 = *(const short8*)(wr + 32);
        const u16* wr2 = lrw + (size_t)(w * 16 + col) * 64 + quad * 8;
        short8 lr0 = *(const short8*)wr2, lr1 = *(const short8*)(wr2 + 32);
        f32x4 bY = bias4(llb + w * 16 + quad * 4);

        const u16* xrA = X + (size_t)ndA * 64 + quad * 8;
        short8 rxA0 = *(const short8*)xrA, rxA1 = *(const short8*)(xrA + 32);

        f32x4 aA = MFMA16(ll0, hbA0, bY, 0, 0, 0);
        aA = MFMA16(ll1, hbA1, aA, 0, 0, 0);
        aA = MFMA16(lr0, rxA0, aA, 0, 0, 0);
        aA = MFMA16(lr1, rxA1, aA, 0, 0, 0);

        u32 yA0 = pack_relu(aA[0], aA[1]), yA1 = pack_relu(aA[2], aA[3]);
        if (act) *(uint2*)(Y1 + (size_t)nodeA * 64 + w * 16 + quad * 4) = (uint2){yA0, yA1};
        xwrite(bufY, 64, col, quad, w, yA0, yA1);
        __syncthreads();

        const u16* wp = pw + (size_t)(w * 16 + col) * 64 + quad * 8;
        short8 p0 = *(const short8*)wp, p1 = *(const short8*)(wp + 32);
        f32x4 bp = bias4(pb + w * 16 + quad * 4);

        short8 ybA0 = xread(bufY, 64, col, quad, 0);
        short8 ybA1 = xread(bufY, 64, col, quad, 1);

        f32x4 a2A = MFMA16(p0, ybA0, bp, 0, 0, 0);
        a2A = MFMA16(p1, ybA1, a2A, 0, 0, 0);

        if (act) *(uint2*)(XP2 + (size_t)nodeA * 64 + w * 16 + quad * 4) =
            (uint2){pack_relu(a2A[0], a2A[1]), pack_relu(a2A[2], a2A[3])};
    }
}

// ---------------------------------------------------------------------------
// lstm_post: layer-2 LSTM + fused Y2[128] -> T1[192] -> T2[64] -> out[64] f32
// ---------------------------------------------------------------------------
__global__ __launch_bounds__(256, 4) void lstm_post(
    const u16* __restrict__ xp, const int* __restrict__ src,
    const u16* __restrict__ wihs, const u16* __restrict__ whhs,
    const u16* __restrict__ bih, const u16* __restrict__ bhh,
    const u16* __restrict__ Y1,                                  // [N,64]
    const u16* __restrict__ llw2, const u16* __restrict__ llb2,
    const u16* __restrict__ lrw2,                                // [128,64],[128],[128,64]
    const u16* __restrict__ w1m, const u16* __restrict__ b1m,    // [192,128],[192]
    const u16* __restrict__ w2m, const u16* __restrict__ b2m,    // [64,192],[64]
    const u16* __restrict__ w3m, const u16* __restrict__ b3m,    // [64,64],[64]
    float* __restrict__ outp, int N)
{
    __shared__ u16 xs[16 * 1024];       // 32KB staged x
    __shared__ float lds_b[256];        // 1KB
    __shared__ u16 lds_h[2][16 * 64];   // 4KB
    u16* bufA = xs;                     // 4KB Y2 exchange (alias; reused for T2 @ stride 64)
    u16* bufB = xs + 2048;              // 6KB T1 exchange (alias)

    LSTMS_PROLOGUE
    LSTMS_CORE_LOOP

    // ---- epilogue ----
    {
        const u16* yrA = Y1 + (size_t)ndA * 64 + quad * 8;
        short8 ryA0 = *(const short8*)yrA, ryA1 = *(const short8*)(yrA + 32);

        // Y2 tiles jt = 2w, 2w+1
#pragma unroll
        for (int ti = 0; ti < 2; ++ti) {
            int jt = 2 * w + ti;
            const u16* wr = llw2 + (size_t)(jt * 16 + col) * 64 + quad * 8;
            short8 l0 = *(const short8*)wr, l1 = *(const short8*)(wr + 32);
            const u16* wr2 = lrw2 + (size_t)(jt * 16 + col) * 64 + quad * 8;
            short8 r0 = *(const short8*)wr2, r1 = *(const short8*)(wr2 + 32);
            f32x4 b0 = bias4(llb2 + jt * 16 + quad * 4);
            f32x4 aA = MFMA16(l0, hbA0, b0, 0, 0, 0);
            aA = MFMA16(l1, hbA1, aA, 0, 0, 0);
            aA = MFMA16(r0, ryA0, aA, 0, 0, 0);
            aA = MFMA16(r1, ryA1, aA, 0, 0, 0);
            xwrite(bufA, 128, col, quad, jt, pack_relu(aA[0], aA[1]), pack_relu(aA[2], aA[3]));
        }
        __syncthreads();

        short8 y2A[4];
#pragma unroll
        for (int kc = 0; kc < 4; ++kc) y2A[kc] = xread(bufA, 128, col, quad, kc);

        // T1 tiles jt = 3w..3w+2, K=128
#pragma unroll
        for (int ti = 0; ti < 3; ++ti) {
            int jt = 3 * w + ti;
            const u16* wr = w1m + (size_t)(jt * 16 + col) * 128 + quad * 8;
            short8 wk[4];
#pragma unroll
            for (int kc = 0; kc < 4; ++kc) wk[kc] = *(const short8*)(wr + kc * 32);
            f32x4 b1v = bias4(b1m + jt * 16 + quad * 4);
            f32x4 aA = b1v;
#pragma unroll
            for (int kc = 0; kc < 4; ++kc) aA = MFMA16(wk[kc], y2A[kc], aA, 0, 0, 0);
            xwrite(bufB, 192, col, quad, jt, pack_relu(aA[0], aA[1]), pack_relu(aA[2], aA[3]));
        }
        __syncthreads();

        short8 t1A[6];
#pragma unroll
        for (int kc = 0; kc < 6; ++kc) t1A[kc] = xread(bufB, 192, col, quad, kc);

        // T2 tile jt=w, K=192 (bufA reuse @ stride 64 — Y2 reads completed pre-barrier)
        {
            const u16* wr = w2m + (size_t)(w * 16 + col) * 192 + quad * 8;
            f32x4 b2v = bias4(b2m + w * 16 + quad * 4);
            f32x4 aA = b2v;
#pragma unroll
            for (int kc = 0; kc < 6; ++kc) {
                short8 wk = *(const short8*)(wr + kc * 32);
                aA = MFMA16(wk, t1A[kc], aA, 0, 0, 0);
            }
            xwrite(bufA, 64, col, quad, w, pack_relu(aA[0], aA[1]), pack_relu(aA[2], aA[3]));
        }
        __syncthreads();

        short8 t2A0 = xread(bufA, 64, col, quad, 0);
        short8 t2A1 = xread(bufA, 64, col, quad, 1);
        // out tile jt=w, K=64, f32 store
        {
            const u16* wr = w3m + (size_t)(w * 16 + col) * 64 + quad * 8;
            short8 l0 = *(const short8*)wr, l1 = *(const short8*)(wr + 32);
            f32x4 b3v = bias4(b3m + w * 16 + quad * 4);
            f32x4 aA = MFMA16(l0, t2A0, b3v, 0, 0, 0);
            aA = MFMA16(l1, t2A1, aA, 0, 0, 0);
            if (act) {
                float4 oA;
                oA.x = fmaxf(aA[0], 0.f); oA.y = fmaxf(aA[1], 0.f);
                oA.z = fmaxf(aA[2], 0.f); oA.w = fmaxf(aA[3], 0.f);
                *(float4*)(outp + (size_t)nodeA * 64 + w * 16 + quad * 4) = oA;
            }
        }
    }
}

// ---------------------------------------------------------------------------
extern "C" void kernel_launch(void* const* d_in, const int* in_sizes, int n_in,
                              void* d_out, int out_size, void* d_ws, size_t ws_size,
                              hipStream_t stream)
{
    const u16* x       = (const u16*)d_in[0];
    const int* edge    = (const int*)d_in[1];
    const u16* p1_pw   = (const u16*)d_in[3];
    const u16* p1_pb   = (const u16*)d_in[4];
    const u16* p1_wih  = (const u16*)d_in[5];
    const u16* p1_whh  = (const u16*)d_in[6];
    const u16* p1_bih  = (const u16*)d_in[7];
    const u16* p1_bhh  = (const u16*)d_in[8];
    const u16* p1_llw  = (const u16*)d_in[9];
    const u16* p1_llb  = (const u16*)d_in[10];
    const u16* p1_lrw  = (const u16*)d_in[11];
    const u16* p2_pw   = (const u16*)d_in[12];
    const u16* p2_pb   = (const u16*)d_in[13];
    const u16* p2_wih  = (const u16*)d_in[14];
    const u16* p2_whh  = (const u16*)d_in[15];
    const u16* p2_bih  = (const u16*)d_in[16];
    const u16* p2_bhh  = (const u16*)d_in[17];
    const u16* p2_llw  = (const u16*)d_in[18];
    const u16* p2_llb  = (const u16*)d_in[19];
    const u16* p2_lrw  = (const u16*)d_in[20];
    const u16* lin1w   = (const u16*)d_in[21];
    const u16* lin1b   = (const u16*)d_in[22];
    const u16* lin2w   = (const u16*)d_in[23];
    const u16* lin2b   = (const u16*)d_in[24];
    const u16* lin3w   = (const u16*)d_in[25];
    const u16* lin3b   = (const u16*)d_in[26];
    (void)n_in; (void)ws_size;

    const int N  = in_sizes[0] / 64;     // 50000
    const int E2 = in_sizes[1];          // 1600000
    const int* srcIdx = edge;

    // workspace: scaled weights 128KB @0; xp1 @1MB; xp2 @8MB; Y1 @15MB
    char* w = (char*)d_ws;
    u16* wss   = (u16*)(w);
    u16* xp1   = (u16*)(w + 1u  * 1024 * 1024);
    u16* xp2   = (u16*)(w + 8u  * 1024 * 1024);
    u16* bufY1 = (u16*)(w + 15u * 1024 * 1024);
    u16* wih1s = wss;
    u16* whh1s = wss + 16384;
    u16* wih2s = wss + 32768;
    u16* whh2s = wss + 49152;

    float* out_h    = (float*)d_out;
    float* out_edge = (float*)d_out + (size_t)N * 64;
    (void)out_size;

    const int gb  = (N + 63) / 64;       // 782 (xp1 GEMM blocks)
    const int gbl = (N + 15) / 16;       // 3125 (lstm blocks, 16 nodes each)
    const int n4 = E2 / 4;
    const int eb = (n4 + 255) / 256;     // 1563

    dim3 block(256);

    hipLaunchKernelGGL(k_pre, dim3(gb + eb + 64), block, 0, stream,
                       x, p1_pw, p1_pb, xp1, N, gb,
                       edge, out_edge, n4, eb,
                       p1_wih, p1_whh, p2_wih, p2_whh, wss);
    hipLaunchKernelGGL(lstm_mid, dim3(gbl), block, 0, stream,
                       xp1, srcIdx, wih1s, whh1s, p1_bih, p1_bhh,
                       x, p1_llw, p1_llb, p1_lrw, p2_pw, p2_pb, bufY1, xp2, N);
    hipLaunchKernelGGL(lstm_post, dim3(gbl), block, 0, stream,
                       xp2, srcIdx, wih2s, whh2s, p2_bih, p2_bhh,
                       bufY1, p2_llw, p2_llb, p2_lrw,
                       lin1w, lin1b, lin2w, lin2b, lin3w, lin3b, out_h, N);
}